// Round 1
// baseline (1318.307 us; speedup 1.0000x reference)
//
#include <hip/hip_runtime.h>

typedef unsigned short u16;
typedef unsigned int   u32;
typedef float f32x4 __attribute__((ext_vector_type(4)));
typedef short s16x8 __attribute__((ext_vector_type(8)));

#define D_MODEL 1024
#define NHEADS  16
#define DK      64
#define SEQ     2048
#define BATCH   4
#define MROWS   (BATCH * SEQ)   // 8192

__device__ __forceinline__ u16 f2b(float f) {
    u32 u = __builtin_bit_cast(u32, f);
    u32 r = (u + 0x7fffu + ((u >> 16) & 1u)) >> 16;
    return (u16)r;
}
__device__ __forceinline__ float b2f(u16 h) {
    u32 u = ((u32)h) << 16;
    return __builtin_bit_cast(float, u);
}

// ---------------- fp32 -> bf16 conversion (vectorized, 4 elems/thread) ----------
__global__ __launch_bounds__(256)
void cvt_kernel(const float* __restrict__ in, u16* __restrict__ out, int n4) {
    int i = blockIdx.x * 256 + threadIdx.x;
    if (i >= n4) return;
    const float4 v = reinterpret_cast<const float4*>(in)[i];
    u32 lo = (u32)f2b(v.x) | ((u32)f2b(v.y) << 16);
    u32 hi = (u32)f2b(v.z) | ((u32)f2b(v.w) << 16);
    reinterpret_cast<uint2*>(out)[i] = make_uint2(lo, hi);
}

// ---------------- bf16 MFMA NT GEMM: C[m,n] = sum_k A[m,k]*W[n,k] + bias[n] (+resid)
#define BM 128
#define BN 128
#define BK 32
#define LDAP (BK + 8)   // pad 8 bf16 = 16B to break power-of-2 LDS strides

__global__ __launch_bounds__(256)
void gemm_bf16_nt(const u16* __restrict__ A, const u16* __restrict__ W,
                  const float* __restrict__ bias, const float* __restrict__ resid,
                  u16* __restrict__ outB, float* __restrict__ outF,
                  int M, int N, int K)
{
    __shared__ u16 As[BM][LDAP];
    __shared__ u16 Bs[BN][LDAP];
    const int t    = threadIdx.x;
    const int lane = t & 63;
    const int wave = t >> 6;
    const int wr = wave >> 1, wc = wave & 1;          // 2x2 wave grid, 64x64 each
    const int m0 = blockIdx.y * BM, n0 = blockIdx.x * BN;

    const int r0 = t >> 2;            // staging row 0..63 (and +64)
    const int kc = (t & 3) * 8;       // bf16 col offset within BK (16B chunks)

    f32x4 acc[4][4];
    #pragma unroll
    for (int i = 0; i < 4; i++)
        #pragma unroll
        for (int j = 0; j < 4; j++)
            acc[i][j] = (f32x4){0.f, 0.f, 0.f, 0.f};

    const int quad = lane >> 4;
    const int rlo  = lane & 15;
    const int koff = quad * 8;

    for (int k0 = 0; k0 < K; k0 += BK) {
        const uint4 va0 = *reinterpret_cast<const uint4*>(A + (long)(m0 + r0)      * K + k0 + kc);
        const uint4 va1 = *reinterpret_cast<const uint4*>(A + (long)(m0 + r0 + 64) * K + k0 + kc);
        const uint4 vb0 = *reinterpret_cast<const uint4*>(W + (long)(n0 + r0)      * K + k0 + kc);
        const uint4 vb1 = *reinterpret_cast<const uint4*>(W + (long)(n0 + r0 + 64) * K + k0 + kc);
        *reinterpret_cast<uint4*>(&As[r0][kc])      = va0;
        *reinterpret_cast<uint4*>(&As[r0 + 64][kc]) = va1;
        *reinterpret_cast<uint4*>(&Bs[r0][kc])      = vb0;
        *reinterpret_cast<uint4*>(&Bs[r0 + 64][kc]) = vb1;
        __syncthreads();

        s16x8 af[4], bf[4];
        #pragma unroll
        for (int i = 0; i < 4; i++)
            af[i] = *reinterpret_cast<const s16x8*>(&As[wr * 64 + i * 16 + rlo][koff]);
        #pragma unroll
        for (int j = 0; j < 4; j++)
            bf[j] = *reinterpret_cast<const s16x8*>(&Bs[wc * 64 + j * 16 + rlo][koff]);

        #pragma unroll
        for (int i = 0; i < 4; i++)
            #pragma unroll
            for (int j = 0; j < 4; j++)
                acc[i][j] = __builtin_amdgcn_mfma_f32_16x16x32_bf16(af[i], bf[j], acc[i][j], 0, 0, 0);
        __syncthreads();
    }

    // epilogue: C/D layout col=lane&15, row=quad*4+reg  [verified m89/m91]
    #pragma unroll
    for (int i = 0; i < 4; i++) {
        #pragma unroll
        for (int j = 0; j < 4; j++) {
            #pragma unroll
            for (int r = 0; r < 4; r++) {
                const int gm = m0 + wr * 64 + i * 16 + quad * 4 + r;
                const int gn = n0 + wc * 64 + j * 16 + rlo;
                float v = acc[i][j][r] + bias[gn];
                if (resid) v += resid[(long)gm * N + gn];
                if (outF) outF[(long)gm * N + gn] = v;
                else      outB[(long)gm * N + gn] = f2b(v);
            }
        }
    }
}

// ---------------- flash attention, fp32 vector compute, bf16 in/out -------------
// grid: (SEQ/64, NHEADS, BATCH), 256 threads. Q tile 64 rows; kv tiles of 64.
__global__ __launch_bounds__(256)
void flash_attn(const u16* __restrict__ Q, const u16* __restrict__ Kg,
                const u16* __restrict__ Vg, u16* __restrict__ C)
{
    __shared__ float Qs[64][66];
    __shared__ float Ps[64][66];
    __shared__ u16   Ks[64][68];
    __shared__ u16   Vs[64][68];

    const int t  = threadIdx.x;
    const int tx = t & 15, ty = t >> 4;
    const int qt = blockIdx.x, h = blockIdx.y, b = blockIdx.z;
    const long colbase = (long)h * DK;
    const long rowb    = (long)b * SEQ;

    // load Q tile, pre-scaled by 1/sqrt(dk) = 0.125
    #pragma unroll
    for (int i = 0; i < 4; i++) {
        int c   = i * 256 + t;        // 1024 chunks of 4 bf16
        int row = c >> 4;
        int col = (c & 15) * 4;
        const uint2 raw = *reinterpret_cast<const uint2*>(
            Q + (rowb + qt * 64 + row) * D_MODEL + colbase + col);
        Qs[row][col + 0] = b2f((u16)(raw.x & 0xffffu)) * 0.125f;
        Qs[row][col + 1] = b2f((u16)(raw.x >> 16))     * 0.125f;
        Qs[row][col + 2] = b2f((u16)(raw.y & 0xffffu)) * 0.125f;
        Qs[row][col + 3] = b2f((u16)(raw.y >> 16))     * 0.125f;
    }

    float mrow[4], lrow[4], o[4][4];
    #pragma unroll
    for (int r = 0; r < 4; r++) {
        mrow[r] = -INFINITY; lrow[r] = 0.f;
        #pragma unroll
        for (int c = 0; c < 4; c++) o[r][c] = 0.f;
    }

    for (int kt = 0; kt < SEQ / 64; kt++) {
        __syncthreads();   // protect Ks/Vs/Ps from previous iteration's readers
        #pragma unroll
        for (int i = 0; i < 4; i++) {
            int c   = i * 256 + t;
            int row = c >> 4;
            int col = (c & 15) * 4;
            long g = (rowb + kt * 64 + row) * D_MODEL + colbase + col;
            *reinterpret_cast<uint2*>(&Ks[row][col]) = *reinterpret_cast<const uint2*>(Kg + g);
            *reinterpret_cast<uint2*>(&Vs[row][col]) = *reinterpret_cast<const uint2*>(Vg + g);
        }
        __syncthreads();

        // S tile: each thread 4x4 of S[64q][64kv]
        float sacc[4][4];
        #pragma unroll
        for (int r = 0; r < 4; r++)
            #pragma unroll
            for (int c = 0; c < 4; c++) sacc[r][c] = 0.f;

        #pragma unroll 8
        for (int kk = 0; kk < 64; kk++) {
            float qv[4], kv[4];
            #pragma unroll
            for (int r = 0; r < 4; r++) qv[r] = Qs[ty * 4 + r][kk];
            #pragma unroll
            for (int c = 0; c < 4; c++) kv[c] = b2f(Ks[tx * 4 + c][kk]);
            #pragma unroll
            for (int r = 0; r < 4; r++)
                #pragma unroll
                for (int c = 0; c < 4; c++)
                    sacc[r][c] = fmaf(qv[r], kv[c], sacc[r][c]);
        }

        // online softmax (row groups of 16 lanes share a q-row set)
        float rmax[4];
        #pragma unroll
        for (int r = 0; r < 4; r++)
            rmax[r] = fmaxf(fmaxf(sacc[r][0], sacc[r][1]), fmaxf(sacc[r][2], sacc[r][3]));
        #pragma unroll
        for (int off = 1; off < 16; off <<= 1)
            #pragma unroll
            for (int r = 0; r < 4; r++)
                rmax[r] = fmaxf(rmax[r], __shfl_xor(rmax[r], off, 16));

        float psum[4];
        #pragma unroll
        for (int r = 0; r < 4; r++) {
            float mnew  = fmaxf(mrow[r], rmax[r]);
            float alpha = __expf(mrow[r] - mnew);
            psum[r] = 0.f;
            #pragma unroll
            for (int c = 0; c < 4; c++) {
                float p = __expf(sacc[r][c] - mnew);
                sacc[r][c] = p;
                psum[r] += p;
            }
            lrow[r] *= alpha;
            mrow[r]  = mnew;
            #pragma unroll
            for (int c = 0; c < 4; c++) o[r][c] *= alpha;
        }
        #pragma unroll
        for (int off = 1; off < 16; off <<= 1)
            #pragma unroll
            for (int r = 0; r < 4; r++)
                psum[r] += __shfl_xor(psum[r], off, 16);
        #pragma unroll
        for (int r = 0; r < 4; r++) lrow[r] += psum[r];

        // P to LDS, then PV
        #pragma unroll
        for (int r = 0; r < 4; r++)
            #pragma unroll
            for (int c = 0; c < 4; c++)
                Ps[ty * 4 + r][tx * 4 + c] = sacc[r][c];
        __syncthreads();

        #pragma unroll 8
        for (int s = 0; s < 64; s++) {
            float pv[4];
            #pragma unroll
            for (int r = 0; r < 4; r++) pv[r] = Ps[ty * 4 + r][s];
            const uint2 raw = *reinterpret_cast<const uint2*>(&Vs[s][tx * 4]);
            const float v0 = b2f((u16)(raw.x & 0xffffu));
            const float v1 = b2f((u16)(raw.x >> 16));
            const float v2 = b2f((u16)(raw.y & 0xffffu));
            const float v3 = b2f((u16)(raw.y >> 16));
            #pragma unroll
            for (int r = 0; r < 4; r++) {
                o[r][0] = fmaf(pv[r], v0, o[r][0]);
                o[r][1] = fmaf(pv[r], v1, o[r][1]);
                o[r][2] = fmaf(pv[r], v2, o[r][2]);
                o[r][3] = fmaf(pv[r], v3, o[r][3]);
            }
        }
    }

    #pragma unroll
    for (int r = 0; r < 4; r++) {
        const float inv = 1.f / lrow[r];
        #pragma unroll
        for (int c = 0; c < 4; c++)
            C[(rowb + qt * 64 + ty * 4 + r) * D_MODEL + colbase + tx * 4 + c] =
                f2b(o[r][c] * inv);
    }
}

// ---------------- row LayerNorm in-place on [8192,1024] fp32 --------------------
__global__ __launch_bounds__(256)
void ln_inplace(float* __restrict__ Y, const float* __restrict__ gamma,
                const float* __restrict__ beta)
{
    const int row = blockIdx.x, t = threadIdx.x;
    float4 v = reinterpret_cast<float4*>(Y + (long)row * D_MODEL)[t];
    float s  = v.x + v.y + v.z + v.w;
    float ss = v.x * v.x + v.y * v.y + v.z * v.z + v.w * v.w;
    #pragma unroll
    for (int off = 32; off > 0; off >>= 1) {
        s  += __shfl_down(s, off, 64);
        ss += __shfl_down(ss, off, 64);
    }
    __shared__ float rs[4], rss[4];
    const int lane = t & 63, w = t >> 6;
    if (lane == 0) { rs[w] = s; rss[w] = ss; }
    __syncthreads();
    const float tot  = rs[0] + rs[1] + rs[2] + rs[3];
    const float tot2 = rss[0] + rss[1] + rss[2] + rss[3];
    const float mu   = tot * (1.f / D_MODEL);
    const float var  = tot2 * (1.f / D_MODEL) - mu * mu;
    const float rstd = rsqrtf(var + 1e-5f);
    const float4 g  = reinterpret_cast<const float4*>(gamma)[t];
    const float4 bb = reinterpret_cast<const float4*>(beta)[t];
    v.x = (v.x - mu) * rstd * g.x + bb.x;
    v.y = (v.y - mu) * rstd * g.y + bb.y;
    v.z = (v.z - mu) * rstd * g.z + bb.z;
    v.w = (v.w - mu) * rstd * g.w + bb.w;
    reinterpret_cast<float4*>(Y + (long)row * D_MODEL)[t] = v;
}

extern "C" void kernel_launch(void* const* d_in, const int* in_sizes, int n_in,
                              void* d_out, int out_size, void* d_ws, size_t ws_size,
                              hipStream_t stream)
{
    const float* x     = (const float*)d_in[0];
    const float* Wq    = (const float*)d_in[1];
    const float* bq    = (const float*)d_in[2];
    const float* Wk    = (const float*)d_in[3];
    const float* bk    = (const float*)d_in[4];
    const float* Wv    = (const float*)d_in[5];
    const float* bv    = (const float*)d_in[6];
    const float* Wo    = (const float*)d_in[7];
    const float* bo    = (const float*)d_in[8];
    const float* gamma = (const float*)d_in[9];
    const float* beta  = (const float*)d_in[10];
    float* out = (float*)d_out;

    u16* ws  = (u16*)d_ws;
    u16* xb  = ws;                                        // [8192,1024] bf16
    u16* Wqb = xb  + (size_t)MROWS * D_MODEL;
    u16* Wkb = Wqb + (size_t)D_MODEL * D_MODEL;
    u16* Wvb = Wkb + (size_t)D_MODEL * D_MODEL;
    u16* Wob = Wvb + (size_t)D_MODEL * D_MODEL;
    u16* Qb  = Wob + (size_t)D_MODEL * D_MODEL;           // [8192,1024] bf16
    u16* Kb  = Qb  + (size_t)MROWS * D_MODEL;
    u16* Vb  = Kb  + (size_t)MROWS * D_MODEL;
    u16* Cb  = Vb  + (size_t)MROWS * D_MODEL;             // ctx bf16
    // total ws: ~92.3 MB

    cvt_kernel<<<MROWS * D_MODEL / 1024, 256, 0, stream>>>(x,  xb,  MROWS * D_MODEL / 4);
    cvt_kernel<<<D_MODEL * D_MODEL / 1024, 256, 0, stream>>>(Wq, Wqb, D_MODEL * D_MODEL / 4);
    cvt_kernel<<<D_MODEL * D_MODEL / 1024, 256, 0, stream>>>(Wk, Wkb, D_MODEL * D_MODEL / 4);
    cvt_kernel<<<D_MODEL * D_MODEL / 1024, 256, 0, stream>>>(Wv, Wvb, D_MODEL * D_MODEL / 4);
    cvt_kernel<<<D_MODEL * D_MODEL / 1024, 256, 0, stream>>>(Wo, Wob, D_MODEL * D_MODEL / 4);

    dim3 gg(D_MODEL / BN, MROWS / BM);
    gemm_bf16_nt<<<gg, 256, 0, stream>>>(xb, Wqb, bq, nullptr, Qb, nullptr, MROWS, D_MODEL, D_MODEL);
    gemm_bf16_nt<<<gg, 256, 0, stream>>>(xb, Wkb, bk, nullptr, Kb, nullptr, MROWS, D_MODEL, D_MODEL);
    gemm_bf16_nt<<<gg, 256, 0, stream>>>(xb, Wvb, bv, nullptr, Vb, nullptr, MROWS, D_MODEL, D_MODEL);

    flash_attn<<<dim3(SEQ / 64, NHEADS, BATCH), 256, 0, stream>>>(Qb, Kb, Vb, Cb);

    gemm_bf16_nt<<<gg, 256, 0, stream>>>(Cb, Wob, bo, x, nullptr, out, MROWS, D_MODEL, D_MODEL);

    ln_inplace<<<MROWS, 256, 0, stream>>>(out, gamma, beta);
}

// Round 2
// 528.194 us; speedup vs baseline: 2.4959x; 2.4959x over previous
//
#include <hip/hip_runtime.h>

typedef unsigned short u16;
typedef unsigned int   u32;
typedef float f32x4 __attribute__((ext_vector_type(4)));
typedef short s16x8 __attribute__((ext_vector_type(8)));

#define D_MODEL 1024
#define NHEADS  16
#define DK      64
#define SEQ     2048
#define BATCH   4
#define MROWS   (BATCH * SEQ)   // 8192

// 0.125 (1/sqrt(dk)) * log2(e) — softmax done in exp2 domain
#define C2 0.18033688011112042f

#if __has_builtin(__builtin_amdgcn_exp2f)
#define EXP2(x) __builtin_amdgcn_exp2f(x)
#else
#define EXP2(x) exp2f(x)
#endif

__device__ __forceinline__ u16 f2b(float f) {           // RNE
    u32 u = __builtin_bit_cast(u32, f);
    u32 r = (u + 0x7fffu + ((u >> 16) & 1u)) >> 16;
    return (u16)r;
}
__device__ __forceinline__ u16 f2b_trunc(float f) {     // truncate (1 instr)
    return (u16)(__builtin_bit_cast(u32, f) >> 16);
}
__device__ __forceinline__ float b2f(u16 h) {
    u32 u = ((u32)h) << 16;
    return __builtin_bit_cast(float, u);
}

// ---------------- fp32 -> bf16 conversion ----------
__global__ __launch_bounds__(256)
void cvt_kernel(const float* __restrict__ in, u16* __restrict__ out, int n4) {
    int i = blockIdx.x * 256 + threadIdx.x;
    if (i >= n4) return;
    const float4 v = reinterpret_cast<const float4*>(in)[i];
    u32 lo = (u32)f2b(v.x) | ((u32)f2b(v.y) << 16);
    u32 hi = (u32)f2b(v.z) | ((u32)f2b(v.w) << 16);
    reinterpret_cast<uint2*>(out)[i] = make_uint2(lo, hi);
}

// ---------------- bf16 MFMA NT GEMM (unchanged from R1) ----------
#define BM 128
#define BN 128
#define BK 32
#define LDAP (BK + 8)

__global__ __launch_bounds__(256)
void gemm_bf16_nt(const u16* __restrict__ A, const u16* __restrict__ W,
                  const float* __restrict__ bias, const float* __restrict__ resid,
                  u16* __restrict__ outB, float* __restrict__ outF,
                  int M, int N, int K)
{
    __shared__ u16 As[BM][LDAP];
    __shared__ u16 Bs[BN][LDAP];
    const int t    = threadIdx.x;
    const int lane = t & 63;
    const int wave = t >> 6;
    const int wr = wave >> 1, wc = wave & 1;
    const int m0 = blockIdx.y * BM, n0 = blockIdx.x * BN;

    const int r0 = t >> 2;
    const int kc = (t & 3) * 8;

    f32x4 acc[4][4];
    #pragma unroll
    for (int i = 0; i < 4; i++)
        #pragma unroll
        for (int j = 0; j < 4; j++)
            acc[i][j] = (f32x4){0.f, 0.f, 0.f, 0.f};

    const int quad = lane >> 4;
    const int rlo  = lane & 15;
    const int koff = quad * 8;

    for (int k0 = 0; k0 < K; k0 += BK) {
        const uint4 va0 = *reinterpret_cast<const uint4*>(A + (long)(m0 + r0)      * K + k0 + kc);
        const uint4 va1 = *reinterpret_cast<const uint4*>(A + (long)(m0 + r0 + 64) * K + k0 + kc);
        const uint4 vb0 = *reinterpret_cast<const uint4*>(W + (long)(n0 + r0)      * K + k0 + kc);
        const uint4 vb1 = *reinterpret_cast<const uint4*>(W + (long)(n0 + r0 + 64) * K + k0 + kc);
        *reinterpret_cast<uint4*>(&As[r0][kc])      = va0;
        *reinterpret_cast<uint4*>(&As[r0 + 64][kc]) = va1;
        *reinterpret_cast<uint4*>(&Bs[r0][kc])      = vb0;
        *reinterpret_cast<uint4*>(&Bs[r0 + 64][kc]) = vb1;
        __syncthreads();

        s16x8 af[4], bf[4];
        #pragma unroll
        for (int i = 0; i < 4; i++)
            af[i] = *reinterpret_cast<const s16x8*>(&As[wr * 64 + i * 16 + rlo][koff]);
        #pragma unroll
        for (int j = 0; j < 4; j++)
            bf[j] = *reinterpret_cast<const s16x8*>(&Bs[wc * 64 + j * 16 + rlo][koff]);

        #pragma unroll
        for (int i = 0; i < 4; i++)
            #pragma unroll
            for (int j = 0; j < 4; j++)
                acc[i][j] = __builtin_amdgcn_mfma_f32_16x16x32_bf16(af[i], bf[j], acc[i][j], 0, 0, 0);
        __syncthreads();
    }

    #pragma unroll
    for (int i = 0; i < 4; i++) {
        #pragma unroll
        for (int j = 0; j < 4; j++) {
            #pragma unroll
            for (int r = 0; r < 4; r++) {
                const int gm = m0 + wr * 64 + i * 16 + quad * 4 + r;
                const int gn = n0 + wc * 64 + j * 16 + rlo;
                float v = acc[i][j][r] + bias[gn];
                if (resid) v += resid[(long)gm * N + gn];
                if (outF) outF[(long)gm * N + gn] = v;
                else      outB[(long)gm * N + gn] = f2b(v);
            }
        }
    }
}

// ---------------- flash attention, bf16 MFMA ------------------------------------
// Block: 128 Q-rows x 1 head, 4 waves (each wave: 32 Q-rows = 2 m-tiles).
// kv tile = 64. Q A-frags live in registers; Qs LDS is reused as Ps after load.
#define LDF 72   // row stride (u16) for all LDS tiles: 144B = 16B-aligned, 36 words

__global__ __launch_bounds__(256)
void flash_attn_mfma(const u16* __restrict__ Qg, const u16* __restrict__ Kg,
                     const u16* __restrict__ Vg, u16* __restrict__ C)
{
    __shared__ u16 QPs[128][LDF];   // Q tile, then reused as P tile
    __shared__ u16 Ks[64][LDF];
    __shared__ u16 Vt[64][LDF];     // V transposed: Vt[dk][kv]

    const int t    = threadIdx.x;
    const int lane = t & 63;
    const int wave = t >> 6;
    const int quad = lane >> 4;
    const int rlo  = lane & 15;
    const int qt = blockIdx.x, h = blockIdx.y, b = blockIdx.z;
    const long colbase = (long)h * DK;
    const long rowb    = (long)b * SEQ;
    const long qrow0   = rowb + (long)qt * 128;

    // ---- stage Q tile (once), pull A-frags into registers ----
    #pragma unroll
    for (int it = 0; it < 4; it++) {
        int c = it * 256 + t;
        int row = c >> 3, colw = (c & 7) * 8;
        *reinterpret_cast<uint4*>(&QPs[row][colw]) =
            *reinterpret_cast<const uint4*>(Qg + (qrow0 + row) * D_MODEL + colbase + colw);
    }
    __syncthreads();
    s16x8 afq[2][2];
    #pragma unroll
    for (int mi = 0; mi < 2; mi++)
        #pragma unroll
        for (int ks = 0; ks < 2; ks++)
            afq[mi][ks] = *reinterpret_cast<const s16x8*>(
                &QPs[wave * 32 + mi * 16 + rlo][ks * 32 + quad * 8]);
    __syncthreads();   // everyone done reading Q before P overwrites begin

    // ones B-frag for row-sum-via-MFMA (bf16 1.0 = 0x3F80)
    s16x8 ones;
    #pragma unroll
    for (int e = 0; e < 8; e++) ones[e] = (short)0x3F80;

    float m2[2][4], l[2][4];
    f32x4 o[2][4];
    #pragma unroll
    for (int mi = 0; mi < 2; mi++)
        #pragma unroll
        for (int r = 0; r < 4; r++) {
            m2[mi][r] = -INFINITY; l[mi][r] = 0.f;
        }
    #pragma unroll
    for (int mi = 0; mi < 2; mi++)
        #pragma unroll
        for (int j = 0; j < 4; j++)
            o[mi][j] = (f32x4){0.f, 0.f, 0.f, 0.f};

    // ---- prefetch kv-tile 0 into registers ----
    uint4 kreg[2];
    uint2 vreg[4];
    #pragma unroll
    for (int it = 0; it < 2; it++) {
        int c = it * 256 + t, row = c >> 3, colw = (c & 7) * 8;
        kreg[it] = *reinterpret_cast<const uint4*>(Kg + (rowb + row) * D_MODEL + colbase + colw);
    }
    #pragma unroll
    for (int it = 0; it < 4; it++) {
        int c = it * 256 + t, kv = c >> 4, col = (c & 15) * 4;
        vreg[it] = *reinterpret_cast<const uint2*>(Vg + (rowb + kv) * D_MODEL + colbase + col);
    }

    for (int kt = 0; kt < SEQ / 64; kt++) {
        __syncthreads();   // previous iteration's readers done
        // ---- write staged K / V(transposed) from prefetch regs ----
        #pragma unroll
        for (int it = 0; it < 2; it++) {
            int c = it * 256 + t, row = c >> 3, colw = (c & 7) * 8;
            *reinterpret_cast<uint4*>(&Ks[row][colw]) = kreg[it];
        }
        #pragma unroll
        for (int it = 0; it < 4; it++) {
            int c = it * 256 + t, kv = c >> 4, col = (c & 15) * 4;
            Vt[col + 0][kv] = (u16)(vreg[it].x & 0xffffu);
            Vt[col + 1][kv] = (u16)(vreg[it].x >> 16);
            Vt[col + 2][kv] = (u16)(vreg[it].y & 0xffffu);
            Vt[col + 3][kv] = (u16)(vreg[it].y >> 16);
        }
        // ---- prefetch kv-tile kt+1 (overlaps with compute below) ----
        if (kt + 1 < SEQ / 64) {
            const long kvb = rowb + (long)(kt + 1) * 64;
            #pragma unroll
            for (int it = 0; it < 2; it++) {
                int c = it * 256 + t, row = c >> 3, colw = (c & 7) * 8;
                kreg[it] = *reinterpret_cast<const uint4*>(Kg + (kvb + row) * D_MODEL + colbase + colw);
            }
            #pragma unroll
            for (int it = 0; it < 4; it++) {
                int c = it * 256 + t, kv = c >> 4, col = (c & 15) * 4;
                vreg[it] = *reinterpret_cast<const uint2*>(Vg + (kvb + kv) * D_MODEL + colbase + col);
            }
        }
        __syncthreads();

        // ---- S = Q K^T (raw, unscaled) ----
        f32x4 sacc[2][4];
        #pragma unroll
        for (int mi = 0; mi < 2; mi++)
            #pragma unroll
            for (int j = 0; j < 4; j++)
                sacc[mi][j] = (f32x4){0.f, 0.f, 0.f, 0.f};
        #pragma unroll
        for (int ks = 0; ks < 2; ks++) {
            s16x8 bfk[4];
            #pragma unroll
            for (int j = 0; j < 4; j++)
                bfk[j] = *reinterpret_cast<const s16x8*>(&Ks[j * 16 + rlo][ks * 32 + quad * 8]);
            #pragma unroll
            for (int mi = 0; mi < 2; mi++)
                #pragma unroll
                for (int j = 0; j < 4; j++)
                    sacc[mi][j] = __builtin_amdgcn_mfma_f32_16x16x32_bf16(
                        afq[mi][ks], bfk[j], sacc[mi][j], 0, 0, 0);
        }

        // ---- online softmax (exp2 domain) ----
        #pragma unroll
        for (int mi = 0; mi < 2; mi++) {
            #pragma unroll
            for (int r = 0; r < 4; r++) {
                float rmax = fmaxf(fmaxf(sacc[mi][0][r], sacc[mi][1][r]),
                                   fmaxf(sacc[mi][2][r], sacc[mi][3][r]));
                rmax = fmaxf(rmax, __shfl_xor(rmax, 1));
                rmax = fmaxf(rmax, __shfl_xor(rmax, 2));
                rmax = fmaxf(rmax, __shfl_xor(rmax, 4));
                rmax = fmaxf(rmax, __shfl_xor(rmax, 8));
                const float mnew  = fmaxf(m2[mi][r], rmax * C2);
                const float alpha = EXP2(m2[mi][r] - mnew);
                m2[mi][r] = mnew;
                l[mi][r] *= alpha;
                #pragma unroll
                for (int j = 0; j < 4; j++) {
                    float p = EXP2(fmaf(sacc[mi][j][r], C2, -mnew));
                    sacc[mi][j][r] = p;
                    o[mi][j][r] *= alpha;
                }
            }
        }
        // ---- P (trunc bf16) -> LDS (reused Q space), C-layout -> A-layout ----
        #pragma unroll
        for (int mi = 0; mi < 2; mi++)
            #pragma unroll
            for (int j = 0; j < 4; j++)
                #pragma unroll
                for (int r = 0; r < 4; r++)
                    QPs[wave * 32 + mi * 16 + quad * 4 + r][j * 16 + rlo] =
                        f2b_trunc(sacc[mi][j][r]);

        // ---- O += P V ; l-rowsum via ones-MFMA (all output cols identical) ----
        f32x4 lacc[2];
        lacc[0] = (f32x4){0.f, 0.f, 0.f, 0.f};
        lacc[1] = (f32x4){0.f, 0.f, 0.f, 0.f};
        #pragma unroll
        for (int ks = 0; ks < 2; ks++) {
            s16x8 afp[2], bfv[4];
            #pragma unroll
            for (int mi = 0; mi < 2; mi++)
                afp[mi] = *reinterpret_cast<const s16x8*>(
                    &QPs[wave * 32 + mi * 16 + rlo][ks * 32 + quad * 8]);
            #pragma unroll
            for (int j = 0; j < 4; j++)
                bfv[j] = *reinterpret_cast<const s16x8*>(&Vt[j * 16 + rlo][ks * 32 + quad * 8]);
            #pragma unroll
            for (int mi = 0; mi < 2; mi++) {
                #pragma unroll
                for (int j = 0; j < 4; j++)
                    o[mi][j] = __builtin_amdgcn_mfma_f32_16x16x32_bf16(
                        afp[mi], bfv[j], o[mi][j], 0, 0, 0);
                lacc[mi] = __builtin_amdgcn_mfma_f32_16x16x32_bf16(
                    afp[mi], ones, lacc[mi], 0, 0, 0);
            }
        }
        #pragma unroll
        for (int mi = 0; mi < 2; mi++)
            #pragma unroll
            for (int r = 0; r < 4; r++)
                l[mi][r] += lacc[mi][r];
    }

    // ---- epilogue: O / l -> bf16 ctx ----
    #pragma unroll
    for (int mi = 0; mi < 2; mi++)
        #pragma unroll
        for (int r = 0; r < 4; r++) {
            const float inv = 1.f / l[mi][r];
            const long grow = qrow0 + wave * 32 + mi * 16 + quad * 4 + r;
            #pragma unroll
            for (int j = 0; j < 4; j++)
                C[grow * D_MODEL + colbase + j * 16 + rlo] = f2b(o[mi][j][r] * inv);
        }
}

// ---------------- row LayerNorm in-place ----------------------------------------
__global__ __launch_bounds__(256)
void ln_inplace(float* __restrict__ Y, const float* __restrict__ gamma,
                const float* __restrict__ beta)
{
    const int row = blockIdx.x, t = threadIdx.x;
    float4 v = reinterpret_cast<float4*>(Y + (long)row * D_MODEL)[t];
    float s  = v.x + v.y + v.z + v.w;
    float ss = v.x * v.x + v.y * v.y + v.z * v.z + v.w * v.w;
    #pragma unroll
    for (int off = 32; off > 0; off >>= 1) {
        s  += __shfl_down(s, off, 64);
        ss += __shfl_down(ss, off, 64);
    }
    __shared__ float rs[4], rss[4];
    const int lane = t & 63, w = t >> 6;
    if (lane == 0) { rs[w] = s; rss[w] = ss; }
    __syncthreads();
    const float tot  = rs[0] + rs[1] + rs[2] + rs[3];
    const float tot2 = rss[0] + rss[1] + rss[2] + rss[3];
    const float mu   = tot * (1.f / D_MODEL);
    const float var  = tot2 * (1.f / D_MODEL) - mu * mu;
    const float rstd = rsqrtf(var + 1e-5f);
    const float4 g  = reinterpret_cast<const float4*>(gamma)[t];
    const float4 bb = reinterpret_cast<const float4*>(beta)[t];
    v.x = (v.x - mu) * rstd * g.x + bb.x;
    v.y = (v.y - mu) * rstd * g.y + bb.y;
    v.z = (v.z - mu) * rstd * g.z + bb.z;
    v.w = (v.w - mu) * rstd * g.w + bb.w;
    reinterpret_cast<float4*>(Y + (long)row * D_MODEL)[t] = v;
}

extern "C" void kernel_launch(void* const* d_in, const int* in_sizes, int n_in,
                              void* d_out, int out_size, void* d_ws, size_t ws_size,
                              hipStream_t stream)
{
    const float* x     = (const float*)d_in[0];
    const float* Wq    = (const float*)d_in[1];
    const float* bq    = (const float*)d_in[2];
    const float* Wk    = (const float*)d_in[3];
    const float* bk    = (const float*)d_in[4];
    const float* Wv    = (const float*)d_in[5];
    const float* bv    = (const float*)d_in[6];
    const float* Wo    = (const float*)d_in[7];
    const float* bo    = (const float*)d_in[8];
    const float* gamma = (const float*)d_in[9];
    const float* beta  = (const float*)d_in[10];
    float* out = (float*)d_out;

    u16* ws  = (u16*)d_ws;
    u16* xb  = ws;
    u16* Wqb = xb  + (size_t)MROWS * D_MODEL;
    u16* Wkb = Wqb + (size_t)D_MODEL * D_MODEL;
    u16* Wvb = Wkb + (size_t)D_MODEL * D_MODEL;
    u16* Wob = Wvb + (size_t)D_MODEL * D_MODEL;
    u16* Qb  = Wob + (size_t)D_MODEL * D_MODEL;
    u16* Kb  = Qb  + (size_t)MROWS * D_MODEL;
    u16* Vb  = Kb  + (size_t)MROWS * D_MODEL;
    u16* Cb  = Vb  + (size_t)MROWS * D_MODEL;

    cvt_kernel<<<MROWS * D_MODEL / 1024, 256, 0, stream>>>(x,  xb,  MROWS * D_MODEL / 4);
    cvt_kernel<<<D_MODEL * D_MODEL / 1024, 256, 0, stream>>>(Wq, Wqb, D_MODEL * D_MODEL / 4);
    cvt_kernel<<<D_MODEL * D_MODEL / 1024, 256, 0, stream>>>(Wk, Wkb, D_MODEL * D_MODEL / 4);
    cvt_kernel<<<D_MODEL * D_MODEL / 1024, 256, 0, stream>>>(Wv, Wvb, D_MODEL * D_MODEL / 4);
    cvt_kernel<<<D_MODEL * D_MODEL / 1024, 256, 0, stream>>>(Wo, Wob, D_MODEL * D_MODEL / 4);

    dim3 gg(D_MODEL / BN, MROWS / BM);
    gemm_bf16_nt<<<gg, 256, 0, stream>>>(xb, Wqb, bq, nullptr, Qb, nullptr, MROWS, D_MODEL, D_MODEL);
    gemm_bf16_nt<<<gg, 256, 0, stream>>>(xb, Wkb, bk, nullptr, Kb, nullptr, MROWS, D_MODEL, D_MODEL);
    gemm_bf16_nt<<<gg, 256, 0, stream>>>(xb, Wvb, bv, nullptr, Vb, nullptr, MROWS, D_MODEL, D_MODEL);

    flash_attn_mfma<<<dim3(SEQ / 128, NHEADS, BATCH), 256, 0, stream>>>(Qb, Kb, Vb, Cb);

    gemm_bf16_nt<<<gg, 256, 0, stream>>>(Cb, Wob, bo, x, nullptr, out, MROWS, D_MODEL, D_MODEL);

    ln_inplace<<<MROWS, 256, 0, stream>>>(out, gamma, beta);
}

// Round 5
// 466.622 us; speedup vs baseline: 2.8252x; 1.1320x over previous
//
#include <hip/hip_runtime.h>

typedef unsigned short u16;
typedef unsigned int   u32;
typedef float f32x4 __attribute__((ext_vector_type(4)));
typedef short s16x8 __attribute__((ext_vector_type(8)));

#define D_MODEL 1024
#define NHEADS  16
#define DK      64
#define SEQ     2048
#define BATCH   4
#define MROWS   (BATCH * SEQ)   // 8192

// 0.125 (1/sqrt(dk)) * log2(e) — softmax in exp2 domain
#define C2 0.18033688011112042f

#if __has_builtin(__builtin_amdgcn_exp2f)
#define EXP2(x) __builtin_amdgcn_exp2f(x)
#else
#define EXP2(x) exp2f(x)
#endif

__device__ __forceinline__ u16 f2b(float f) {           // RNE
    u32 u = __builtin_bit_cast(u32, f);
    u32 r = (u + 0x7fffu + ((u >> 16) & 1u)) >> 16;
    return (u16)r;
}
__device__ __forceinline__ u32 pack2_trunc(float a, float b) {
    return (__builtin_bit_cast(u32, a) >> 16) | (__builtin_bit_cast(u32, b) & 0xffff0000u);
}

// ---------------- fp32 -> bf16 conversion ----------
__global__ __launch_bounds__(256)
void cvt_kernel(const float* __restrict__ in, u16* __restrict__ out, int n4) {
    int i = blockIdx.x * 256 + threadIdx.x;
    if (i >= n4) return;
    const float4 v = reinterpret_cast<const float4*>(in)[i];
    u32 lo = (u32)f2b(v.x) | ((u32)f2b(v.y) << 16);
    u32 hi = (u32)f2b(v.z) | ((u32)f2b(v.w) << 16);
    reinterpret_cast<uint2*>(out)[i] = make_uint2(lo, hi);
}

// ---------------- bf16 MFMA NT GEMM ----------
// outVT != null => write output transposed per-head: VT[((b*16+h)*64+d)*2048 + s]
#define BM 128
#define BN 128
#define BK 32
#define LDAP (BK + 8)

__global__ __launch_bounds__(256)
void gemm_bf16_nt(const u16* __restrict__ A, const u16* __restrict__ W,
                  const float* __restrict__ bias, const float* __restrict__ resid,
                  u16* __restrict__ outB, float* __restrict__ outF,
                  u16* __restrict__ outVT,
                  int M, int N, int K)
{
    __shared__ u16 As[BM][LDAP];
    __shared__ u16 Bs[BN][LDAP];
    const int t    = threadIdx.x;
    const int lane = t & 63;
    const int wave = t >> 6;
    const int wr = wave >> 1, wc = wave & 1;
    const int m0 = blockIdx.y * BM, n0 = blockIdx.x * BN;

    const int r0 = t >> 2;
    const int kc = (t & 3) * 8;

    f32x4 acc[4][4];
    #pragma unroll
    for (int i = 0; i < 4; i++)
        #pragma unroll
        for (int j = 0; j < 4; j++)
            acc[i][j] = (f32x4){0.f, 0.f, 0.f, 0.f};

    const int quad = lane >> 4;
    const int rlo  = lane & 15;
    const int koff = quad * 8;

    for (int k0 = 0; k0 < K; k0 += BK) {
        const uint4 va0 = *reinterpret_cast<const uint4*>(A + (long)(m0 + r0)      * K + k0 + kc);
        const uint4 va1 = *reinterpret_cast<const uint4*>(A + (long)(m0 + r0 + 64) * K + k0 + kc);
        const uint4 vb0 = *reinterpret_cast<const uint4*>(W + (long)(n0 + r0)      * K + k0 + kc);
        const uint4 vb1 = *reinterpret_cast<const uint4*>(W + (long)(n0 + r0 + 64) * K + k0 + kc);
        *reinterpret_cast<uint4*>(&As[r0][kc])      = va0;
        *reinterpret_cast<uint4*>(&As[r0 + 64][kc]) = va1;
        *reinterpret_cast<uint4*>(&Bs[r0][kc])      = vb0;
        *reinterpret_cast<uint4*>(&Bs[r0 + 64][kc]) = vb1;
        __syncthreads();

        s16x8 af[4], bf[4];
        #pragma unroll
        for (int i = 0; i < 4; i++)
            af[i] = *reinterpret_cast<const s16x8*>(&As[wr * 64 + i * 16 + rlo][koff]);
        #pragma unroll
        for (int j = 0; j < 4; j++)
            bf[j] = *reinterpret_cast<const s16x8*>(&Bs[wc * 64 + j * 16 + rlo][koff]);

        #pragma unroll
        for (int i = 0; i < 4; i++)
            #pragma unroll
            for (int j = 0; j < 4; j++)
                acc[i][j] = __builtin_amdgcn_mfma_f32_16x16x32_bf16(af[i], bf[j], acc[i][j], 0, 0, 0);
        __syncthreads();
    }

    if (outVT) {
        // transposed per-head epilogue (V projection): VT[b][h][d][s], 4 s-contig packed
        #pragma unroll
        for (int i = 0; i < 4; i++) {
            #pragma unroll
            for (int j = 0; j < 4; j++) {
                const int gm0 = m0 + wr * 64 + i * 16 + quad * 4;   // s base (mult of 4)
                const int gn  = n0 + wc * 64 + j * 16 + rlo;
                const float bv = bias[gn];
                const int bb = gm0 >> 11, s = gm0 & 2047;
                const int h = gn >> 6, d = gn & 63;
                uint2 w;
                w.x = (u32)f2b(acc[i][j][0] + bv) | ((u32)f2b(acc[i][j][1] + bv) << 16);
                w.y = (u32)f2b(acc[i][j][2] + bv) | ((u32)f2b(acc[i][j][3] + bv) << 16);
                *reinterpret_cast<uint2*>(outVT + ((long)((bb * 16 + h) * 64 + d)) * 2048 + s) = w;
            }
        }
        return;
    }

    #pragma unroll
    for (int i = 0; i < 4; i++) {
        #pragma unroll
        for (int j = 0; j < 4; j++) {
            #pragma unroll
            for (int r = 0; r < 4; r++) {
                const int gm = m0 + wr * 64 + i * 16 + quad * 4 + r;
                const int gn = n0 + wc * 64 + j * 16 + rlo;
                float v = acc[i][j][r] + bias[gn];
                if (resid) v += resid[(long)gm * N + gn];
                if (outF) outF[(long)gm * N + gn] = v;
                else      outB[(long)gm * N + gn] = f2b(v);
            }
        }
    }
}

// ---------------- flash attention, S^T-scheme bf16 MFMA -------------------------
// Block: 128 Q-rows x 1 head, 4 waves (wave: 32 q = 2 mi-blocks). kv tile = 64.
// S^T = K·Q^T  (A=K from LDS, B=Q in regs). C-layout of S^T gives kv-contiguous
// quads -> P stored to Ps[q][kv] with packed b64 writes. V^T pre-transposed
// globally by the V-GEMM epilogue -> staged like K. PV: A=Ps, B=Vts.
#define LDF 72

__global__ __launch_bounds__(256)
void flash_attn_mfma(const u16* __restrict__ Qg, const u16* __restrict__ Kg,
                     const u16* __restrict__ VtG, u16* __restrict__ C)
{
    __shared__ u16 QPs[128][LDF];   // Q tile, then reused as P tile (q-major, kv contig)
    __shared__ u16 Ks[64][LDF];     // K tile  [kv][dk]
    __shared__ u16 Vts[64][LDF];    // V^T tile [d][kv]

    const int t    = threadIdx.x;
    const int lane = t & 63;
    const int wave = t >> 6;
    const int quad = lane >> 4;
    const int rlo  = lane & 15;
    const int qt = blockIdx.x, h = blockIdx.y, b = blockIdx.z;
    const long colbase = (long)h * DK;
    const long rowb    = (long)b * SEQ;
    const long qrow0   = rowb + (long)qt * 128;
    const long hdbase  = ((long)(b * 16 + h) * 64) * 2048;  // VtG: + d*2048 + kv

    // ---- stage Q tile, pull B-frags into registers ----
    #pragma unroll
    for (int it = 0; it < 4; it++) {
        int c = it * 256 + t;
        int row = c >> 3, colw = (c & 7) * 8;
        *reinterpret_cast<uint4*>(&QPs[row][colw]) =
            *reinterpret_cast<const uint4*>(Qg + (qrow0 + row) * D_MODEL + colbase + colw);
    }
    __syncthreads();
    s16x8 bfq[2][2];
    #pragma unroll
    for (int mi = 0; mi < 2; mi++)
        #pragma unroll
        for (int ks = 0; ks < 2; ks++)
            bfq[mi][ks] = *reinterpret_cast<const s16x8*>(
                &QPs[wave * 32 + mi * 16 + rlo][ks * 32 + quad * 8]);
    __syncthreads();   // all Q reads done before P overwrites

    float m2[2] = {-INFINITY, -INFINITY};
    float l[2]  = {0.f, 0.f};      // per-lane PARTIAL row-sum (cross-quad reduce deferred)
    f32x4 o[2][4];
    #pragma unroll
    for (int mi = 0; mi < 2; mi++)
        #pragma unroll
        for (int db = 0; db < 4; db++)
            o[mi][db] = (f32x4){0.f, 0.f, 0.f, 0.f};

    // ---- prefetch kv-tile 0 ----
    uint4 kreg[2], vreg[2];
    #pragma unroll
    for (int it = 0; it < 2; it++) {
        int c = it * 256 + t, row = c >> 3, colw = (c & 7) * 8;
        kreg[it] = *reinterpret_cast<const uint4*>(Kg + (rowb + row) * D_MODEL + colbase + colw);
        vreg[it] = *reinterpret_cast<const uint4*>(VtG + hdbase + (long)row * 2048 + colw);
    }

    for (int kt = 0; kt < SEQ / 64; kt++) {
        __syncthreads();
        #pragma unroll
        for (int it = 0; it < 2; it++) {
            int c = it * 256 + t, row = c >> 3, colw = (c & 7) * 8;
            *reinterpret_cast<uint4*>(&Ks[row][colw])  = kreg[it];
            *reinterpret_cast<uint4*>(&Vts[row][colw]) = vreg[it];
        }
        if (kt + 1 < SEQ / 64) {
            const long kvoff = (long)(kt + 1) * 64;
            #pragma unroll
            for (int it = 0; it < 2; it++) {
                int c = it * 256 + t, row = c >> 3, colw = (c & 7) * 8;
                kreg[it] = *reinterpret_cast<const uint4*>(
                    Kg + (rowb + kvoff + row) * D_MODEL + colbase + colw);
                vreg[it] = *reinterpret_cast<const uint4*>(
                    VtG + hdbase + (long)row * 2048 + kvoff + colw);
            }
        }
        __syncthreads();

        // ---- S^T = K Q^T : sc[mi][kb] => S^T[kv = kb*16+quad*4+r][q = w*32+mi*16+rlo]
        f32x4 sc[2][4];
        #pragma unroll
        for (int mi = 0; mi < 2; mi++)
            #pragma unroll
            for (int kb = 0; kb < 4; kb++)
                sc[mi][kb] = (f32x4){0.f, 0.f, 0.f, 0.f};
        #pragma unroll
        for (int ks = 0; ks < 2; ks++) {
            s16x8 afk[4];
            #pragma unroll
            for (int kb = 0; kb < 4; kb++)
                afk[kb] = *reinterpret_cast<const s16x8*>(&Ks[kb * 16 + rlo][ks * 32 + quad * 8]);
            #pragma unroll
            for (int mi = 0; mi < 2; mi++)
                #pragma unroll
                for (int kb = 0; kb < 4; kb++)
                    sc[mi][kb] = __builtin_amdgcn_mfma_f32_16x16x32_bf16(
                        afk[kb], bfq[mi][ks], sc[mi][kb], 0, 0, 0);
        }

        // ---- online softmax: each lane owns ONE q (=rlo) per mi, 16 kv values ----
        float alpha[2];
        #pragma unroll
        for (int mi = 0; mi < 2; mi++) {
            float rmax = sc[mi][0][0];
            #pragma unroll
            for (int kb = 0; kb < 4; kb++)
                #pragma unroll
                for (int r = 0; r < 4; r++)
                    rmax = fmaxf(rmax, sc[mi][kb][r]);
            rmax = fmaxf(rmax, __shfl_xor(rmax, 16));
            rmax = fmaxf(rmax, __shfl_xor(rmax, 32));
            const float mnew = fmaxf(m2[mi], rmax * C2);
            alpha[mi] = EXP2(m2[mi] - mnew);
            m2[mi] = mnew;
            float ps = 0.f;
            #pragma unroll
            for (int kb = 0; kb < 4; kb++) {
                float p0 = EXP2(fmaf(sc[mi][kb][0], C2, -mnew));
                float p1 = EXP2(fmaf(sc[mi][kb][1], C2, -mnew));
                float p2 = EXP2(fmaf(sc[mi][kb][2], C2, -mnew));
                float p3 = EXP2(fmaf(sc[mi][kb][3], C2, -mnew));
                ps += (p0 + p1) + (p2 + p3);
                uint2 w;
                w.x = pack2_trunc(p0, p1);
                w.y = pack2_trunc(p2, p3);
                *reinterpret_cast<uint2*>(&QPs[wave * 32 + mi * 16 + rlo][kb * 16 + quad * 4]) = w;
            }
            l[mi] = l[mi] * alpha[mi] + ps;
        }

        // ---- rescale O by alpha (alpha lives at lane rlo=q; fetch per quad-row) ----
        #pragma unroll
        for (int mi = 0; mi < 2; mi++) {
            #pragma unroll
            for (int r = 0; r < 4; r++) {
                const float ar = __shfl(alpha[mi], (lane & 48) | (quad * 4 + r));
                #pragma unroll
                for (int db = 0; db < 4; db++)
                    o[mi][db][r] *= ar;
            }
        }

        // ---- O += P V : A = Ps (q,kv) , B = Vts (d,kv) ----
        #pragma unroll
        for (int ks = 0; ks < 2; ks++) {
            s16x8 afp[2], bfv[4];
            #pragma unroll
            for (int mi = 0; mi < 2; mi++)
                afp[mi] = *reinterpret_cast<const s16x8*>(
                    &QPs[wave * 32 + mi * 16 + rlo][ks * 32 + quad * 8]);
            #pragma unroll
            for (int db = 0; db < 4; db++)
                bfv[db] = *reinterpret_cast<const s16x8*>(&Vts[db * 16 + rlo][ks * 32 + quad * 8]);
            #pragma unroll
            for (int mi = 0; mi < 2; mi++)
                #pragma unroll
                for (int db = 0; db < 4; db++)
                    o[mi][db] = __builtin_amdgcn_mfma_f32_16x16x32_bf16(
                        afp[mi], bfv[db], o[mi][db], 0, 0, 0);
        }
    }

    // ---- epilogue: finish l reduce, O/l -> bf16 ctx ----
    #pragma unroll
    for (int mi = 0; mi < 2; mi++) {
        float lf = l[mi];
        lf += __shfl_xor(lf, 16);
        lf += __shfl_xor(lf, 32);
        #pragma unroll
        for (int r = 0; r < 4; r++) {
            const float inv = 1.f / __shfl(lf, (lane & 48) | (quad * 4 + r));
            const long grow = qrow0 + wave * 32 + mi * 16 + quad * 4 + r;
            #pragma unroll
            for (int db = 0; db < 4; db++)
                C[grow * D_MODEL + colbase + db * 16 + rlo] = f2b(o[mi][db][r] * inv);
        }
    }
}

// ---------------- row LayerNorm in-place ----------------------------------------
__global__ __launch_bounds__(256)
void ln_inplace(float* __restrict__ Y, const float* __restrict__ gamma,
                const float* __restrict__ beta)
{
    const int row = blockIdx.x, t = threadIdx.x;
    float4 v = reinterpret_cast<float4*>(Y + (long)row * D_MODEL)[t];
    float s  = v.x + v.y + v.z + v.w;
    float ss = v.x * v.x + v.y * v.y + v.z * v.z + v.w * v.w;
    #pragma unroll
    for (int off = 32; off > 0; off >>= 1) {
        s  += __shfl_down(s, off, 64);
        ss += __shfl_down(ss, off, 64);
    }
    __shared__ float rs[4], rss[4];
    const int lane = t & 63, w = t >> 6;
    if (lane == 0) { rs[w] = s; rss[w] = ss; }
    __syncthreads();
    const float tot  = rs[0] + rs[1] + rs[2] + rs[3];
    const float tot2 = rss[0] + rss[1] + rss[2] + rss[3];
    const float mu   = tot * (1.f / D_MODEL);
    const float var  = tot2 * (1.f / D_MODEL) - mu * mu;
    const float rstd = rsqrtf(var + 1e-5f);
    const float4 g  = reinterpret_cast<const float4*>(gamma)[t];
    const float4 bb = reinterpret_cast<const float4*>(beta)[t];
    v.x = (v.x - mu) * rstd * g.x + bb.x;
    v.y = (v.y - mu) * rstd * g.y + bb.y;
    v.z = (v.z - mu) * rstd * g.z + bb.z;
    v.w = (v.w - mu) * rstd * g.w + bb.w;
    reinterpret_cast<float4*>(Y + (long)row * D_MODEL)[t] = v;
}

extern "C" void kernel_launch(void* const* d_in, const int* in_sizes, int n_in,
                              void* d_out, int out_size, void* d_ws, size_t ws_size,
                              hipStream_t stream)
{
    const float* x     = (const float*)d_in[0];
    const float* Wq    = (const float*)d_in[1];
    const float* bq    = (const float*)d_in[2];
    const float* Wk    = (const float*)d_in[3];
    const float* bk    = (const float*)d_in[4];
    const float* Wv    = (const float*)d_in[5];
    const float* bv    = (const float*)d_in[6];
    const float* Wo    = (const float*)d_in[7];
    const float* bo    = (const float*)d_in[8];
    const float* gamma = (const float*)d_in[9];
    const float* beta  = (const float*)d_in[10];
    float* out = (float*)d_out;

    u16* ws  = (u16*)d_ws;
    u16* xb  = ws;
    u16* Wqb = xb  + (size_t)MROWS * D_MODEL;
    u16* Wkb = Wqb + (size_t)D_MODEL * D_MODEL;
    u16* Wvb = Wkb + (size_t)D_MODEL * D_MODEL;
    u16* Wob = Wvb + (size_t)D_MODEL * D_MODEL;
    u16* Qb  = Wob + (size_t)D_MODEL * D_MODEL;
    u16* Kb  = Qb  + (size_t)MROWS * D_MODEL;
    u16* VtB = Kb  + (size_t)MROWS * D_MODEL;    // V^T in [b][h][d][s] layout
    u16* Cb  = VtB + (size_t)MROWS * D_MODEL;

    cvt_kernel<<<MROWS * D_MODEL / 1024, 256, 0, stream>>>(x,  xb,  MROWS * D_MODEL / 4);
    cvt_kernel<<<D_MODEL * D_MODEL / 1024, 256, 0, stream>>>(Wq, Wqb, D_MODEL * D_MODEL / 4);
    cvt_kernel<<<D_MODEL * D_MODEL / 1024, 256, 0, stream>>>(Wk, Wkb, D_MODEL * D_MODEL / 4);
    cvt_kernel<<<D_MODEL * D_MODEL / 1024, 256, 0, stream>>>(Wv, Wvb, D_MODEL * D_MODEL / 4);
    cvt_kernel<<<D_MODEL * D_MODEL / 1024, 256, 0, stream>>>(Wo, Wob, D_MODEL * D_MODEL / 4);

    dim3 gg(D_MODEL / BN, MROWS / BM);
    gemm_bf16_nt<<<gg, 256, 0, stream>>>(xb, Wqb, bq, nullptr, Qb, nullptr, nullptr, MROWS, D_MODEL, D_MODEL);
    gemm_bf16_nt<<<gg, 256, 0, stream>>>(xb, Wkb, bk, nullptr, Kb, nullptr, nullptr, MROWS, D_MODEL, D_MODEL);
    gemm_bf16_nt<<<gg, 256, 0, stream>>>(xb, Wvb, bv, nullptr, nullptr, nullptr, VtB, MROWS, D_MODEL, D_MODEL);

    flash_attn_mfma<<<dim3(SEQ / 128, NHEADS, BATCH), 256, 0, stream>>>(Qb, Kb, VtB, Cb);

    gemm_bf16_nt<<<gg, 256, 0, stream>>>(Cb, Wob, bo, x, nullptr, out, nullptr, MROWS, D_MODEL, D_MODEL);

    ln_inplace<<<MROWS, 256, 0, stream>>>(out, gamma, beta);
}

// Round 6
// 436.550 us; speedup vs baseline: 3.0198x; 1.0689x over previous
//
#include <hip/hip_runtime.h>

typedef unsigned short u16;
typedef unsigned int   u32;
typedef float f32x4 __attribute__((ext_vector_type(4)));
typedef short s16x8 __attribute__((ext_vector_type(8)));

#define D_MODEL 1024
#define NHEADS  16
#define DK      64
#define SEQ     2048
#define BATCH   4
#define MROWS   (BATCH * SEQ)   // 8192

// 0.125 (1/sqrt(dk)) * log2(e) — softmax in exp2 domain
#define C2 0.18033688011112042f

#if __has_builtin(__builtin_amdgcn_exp2f)
#define EXP2(x) __builtin_amdgcn_exp2f(x)
#else
#define EXP2(x) exp2f(x)
#endif

// async global->LDS DMA, 16B per lane; dest = wave-uniform base + lane*16
#define GL16(gp, lp) __builtin_amdgcn_global_load_lds( \
    (const __attribute__((address_space(1))) u32*)(gp), \
    (__attribute__((address_space(3))) u32*)(lp), 16, 0, 0)

__device__ __forceinline__ u16 f2b(float f) {           // RNE
    u32 u = __builtin_bit_cast(u32, f);
    u32 r = (u + 0x7fffu + ((u >> 16) & 1u)) >> 16;
    return (u16)r;
}
__device__ __forceinline__ u32 pack2_trunc(float a, float b) {
    return (__builtin_bit_cast(u32, a) >> 16) | (__builtin_bit_cast(u32, b) & 0xffff0000u);
}

// ---------------- fp32 -> bf16 conversion ----------
__global__ __launch_bounds__(256)
void cvt_kernel(const float* __restrict__ in, u16* __restrict__ out, int n4) {
    int i = blockIdx.x * 256 + threadIdx.x;
    if (i >= n4) return;
    const float4 v = reinterpret_cast<const float4*>(in)[i];
    u32 lo = (u32)f2b(v.x) | ((u32)f2b(v.y) << 16);
    u32 hi = (u32)f2b(v.z) | ((u32)f2b(v.w) << 16);
    reinterpret_cast<uint2*>(out)[i] = make_uint2(lo, hi);
}

// ---------------- bf16 MFMA NT GEMM, m97-style global_load_lds staging ----------
// LDS is FRAGMENT-MAJOR: off16(rb, lane) = rb*512 + lane*8, where frag block
// rb maps to rows (rb>>2)*64 + (rb&3)*16 + (lane&15), k = (lane>>4)*8.
// Staging round rr, wave w fills rb = rr*4+w with a single global_load_lds(16B).
// Frag reads are lane-linear -> conflict-free ds_read_b128.
#define BM 128
#define BN 128
#define BK 32

__global__ __launch_bounds__(256)
void gemm_bf16_nt(const u16* __restrict__ A, const u16* __restrict__ W,
                  const float* __restrict__ bias, const float* __restrict__ resid,
                  u16* __restrict__ outB, float* __restrict__ outF,
                  u16* __restrict__ outVT,
                  int M, int N, int K)
{
    __shared__ __align__(16) u16 As[4096];   // 128x32 frag-major
    __shared__ __align__(16) u16 Bs[4096];
    const int t    = threadIdx.x;
    const int lane = t & 63;
    const int wave = t >> 6;
    const int wr = wave >> 1, wc = wave & 1;
    const int m0 = blockIdx.y * BM, n0 = blockIdx.x * BN;
    const int quad = lane >> 4;
    const int rlo  = lane & 15;

    // staging source rows/cols for this thread (round rr=0: rb=wave; rr=1: rb=4+wave)
    const int srow0 = wave * 16 + rlo;          // rb&3 = wave, rb>>2 = 0
    const int scol  = quad * 8;
    const long aoff0 = (long)(m0 + srow0) * K + scol;
    const long aoff1 = (long)(m0 + 64 + srow0) * K + scol;
    const long boff0 = (long)(n0 + srow0) * K + scol;
    const long boff1 = (long)(n0 + 64 + srow0) * K + scol;
    u16* dA0 = &As[wave * 512 + lane * 8];
    u16* dA1 = dA0 + 2048;
    u16* dB0 = &Bs[wave * 512 + lane * 8];
    u16* dB1 = dB0 + 2048;

    f32x4 acc[4][4];
    #pragma unroll
    for (int i = 0; i < 4; i++)
        #pragma unroll
        for (int j = 0; j < 4; j++)
            acc[i][j] = (f32x4){0.f, 0.f, 0.f, 0.f};

    for (int k0 = 0; k0 < K; k0 += BK) {
        __syncthreads();
        GL16(A + aoff0 + k0, dA0);
        GL16(A + aoff1 + k0, dA1);
        GL16(W + boff0 + k0, dB0);
        GL16(W + boff1 + k0, dB1);
        __syncthreads();

        s16x8 af[4], bf[4];
        #pragma unroll
        for (int i = 0; i < 4; i++)
            af[i] = *reinterpret_cast<const s16x8*>(&As[(wr * 4 + i) * 512 + lane * 8]);
        #pragma unroll
        for (int j = 0; j < 4; j++)
            bf[j] = *reinterpret_cast<const s16x8*>(&Bs[(wc * 4 + j) * 512 + lane * 8]);

        #pragma unroll
        for (int i = 0; i < 4; i++)
            #pragma unroll
            for (int j = 0; j < 4; j++)
                acc[i][j] = __builtin_amdgcn_mfma_f32_16x16x32_bf16(af[i], bf[j], acc[i][j], 0, 0, 0);
    }

    if (outVT) {
        // transposed per-head epilogue (V projection): VT[b][h][d][s]
        #pragma unroll
        for (int i = 0; i < 4; i++) {
            #pragma unroll
            for (int j = 0; j < 4; j++) {
                const int gm0 = m0 + wr * 64 + i * 16 + quad * 4;   // s base (mult of 4)
                const int gn  = n0 + wc * 64 + j * 16 + rlo;
                const float bv = bias[gn];
                const int bb = gm0 >> 11, s = gm0 & 2047;
                const int h = gn >> 6, d = gn & 63;
                uint2 w;
                w.x = (u32)f2b(acc[i][j][0] + bv) | ((u32)f2b(acc[i][j][1] + bv) << 16);
                w.y = (u32)f2b(acc[i][j][2] + bv) | ((u32)f2b(acc[i][j][3] + bv) << 16);
                *reinterpret_cast<uint2*>(outVT + ((long)((bb * 16 + h) * 64 + d)) * 2048 + s) = w;
            }
        }
        return;
    }

    #pragma unroll
    for (int i = 0; i < 4; i++) {
        #pragma unroll
        for (int j = 0; j < 4; j++) {
            #pragma unroll
            for (int r = 0; r < 4; r++) {
                const int gm = m0 + wr * 64 + i * 16 + quad * 4 + r;
                const int gn = n0 + wc * 64 + j * 16 + rlo;
                float v = acc[i][j][r] + bias[gn];
                if (resid) v += resid[(long)gm * N + gn];
                if (outF) outF[(long)gm * N + gn] = v;
                else      outB[(long)gm * N + gn] = f2b(v);
            }
        }
    }
}

// ---------------- flash attention: 256q block, 64q/wave, frag-major staging -----
// S^T = K·Q^T (A=K LDS frag-major, B=Q regs). P -> per-wave padded LDS (stride 72,
// 16B-aligned rows, bank-free b64 writes + b128 reads). V^T staged frag-major.
// LDS: Ps 4*64*72=18432 u16 (Q tile [256][64]=16384 staged here first, dead after
// frag extraction) | Ks 4096 | Vts 4096  => 26624 u16 = 53 KB -> 3 blocks/CU.
#define PSTR 72

__global__ __launch_bounds__(256)
void flash_attn_mfma(const u16* __restrict__ Qg, const u16* __restrict__ Kg,
                     const u16* __restrict__ VtG, u16* __restrict__ C)
{
    __shared__ __align__(16) u16 smem[26624];
    u16* Ks  = &smem[18432];
    u16* Vts = &smem[22528];

    const int t    = threadIdx.x;
    const int lane = t & 63;
    const int wave = t >> 6;
    const int quad = lane >> 4;
    const int rlo  = lane & 15;
    const int qt = blockIdx.x, h = blockIdx.y, b = blockIdx.z;
    const long colbase = (long)h * DK;
    const long rowb    = (long)b * SEQ;
    const long qrow0   = rowb + (long)qt * 256;
    const u16* kg    = Kg + rowb * D_MODEL + colbase;
    const u16* vbase = VtG + (long)(b * 16 + h) * 64 * 2048;
    u16* myPs = &smem[wave * 64 * PSTR];

    // ---- stage Q tile [256][64] into smem via DMA ----
    {
        const int qsrow = t >> 3;            // +rr*32
        const int qscol = (t & 7) * 8;
        #pragma unroll
        for (int rr = 0; rr < 8; rr++)
            GL16(Qg + (qrow0 + rr * 32 + qsrow) * D_MODEL + colbase + qscol,
                 &smem[rr * 2048 + t * 8]);
    }
    __syncthreads();
    s16x8 bfq[4][2];
    #pragma unroll
    for (int mi = 0; mi < 4; mi++)
        #pragma unroll
        for (int ks = 0; ks < 2; ks++)
            bfq[mi][ks] = *reinterpret_cast<const s16x8*>(
                &smem[(wave * 64 + mi * 16 + rlo) * 64 + ks * 32 + quad * 8]);

    float m2[4] = {-INFINITY, -INFINITY, -INFINITY, -INFINITY};
    float l[4]  = {0.f, 0.f, 0.f, 0.f};
    f32x4 o[4][4];
    #pragma unroll
    for (int mi = 0; mi < 4; mi++)
        #pragma unroll
        for (int db = 0; db < 4; db++)
            o[mi][db] = (f32x4){0.f, 0.f, 0.f, 0.f};

    // staging addresses (frag-major: dest off16 = ks*2048 + blk*512 + lane*8)
    const long koff  = (long)(wave * 16 + rlo) * D_MODEL + quad * 8;  // + kv0*D_MODEL + ks*32
    const long voff  = (long)(wave * 16 + rlo) * 2048 + quad * 8;     // + kv0 + ks*32
    u16* dK0 = &Ks[wave * 512 + lane * 8];
    u16* dV0 = &Vts[wave * 512 + lane * 8];

    for (int kt = 0; kt < SEQ / 64; kt++) {
        const long kv0 = (long)kt * 64;
        __syncthreads();   // prev iteration's Ks/Vts reads (and Q/Ps reads) done
        GL16(kg + kv0 * D_MODEL + koff,      dK0);
        GL16(kg + kv0 * D_MODEL + koff + 32, dK0 + 2048);
        GL16(vbase + kv0 + voff,             dV0);
        GL16(vbase + kv0 + voff + 32,        dV0 + 2048);
        __syncthreads();

        // ---- K frags (lane-linear, conflict-free) ----
        s16x8 afk[2][4];
        #pragma unroll
        for (int ks = 0; ks < 2; ks++)
            #pragma unroll
            for (int kb = 0; kb < 4; kb++)
                afk[ks][kb] = *reinterpret_cast<const s16x8*>(
                    &Ks[ks * 2048 + kb * 512 + lane * 8]);

        // ---- per-mi: S^T, online softmax, P store ----
        float alpha[4];
        #pragma unroll
        for (int mi = 0; mi < 4; mi++) {
            f32x4 sc[4];
            #pragma unroll
            for (int kb = 0; kb < 4; kb++) sc[kb] = (f32x4){0.f, 0.f, 0.f, 0.f};
            #pragma unroll
            for (int ks = 0; ks < 2; ks++)
                #pragma unroll
                for (int kb = 0; kb < 4; kb++)
                    sc[kb] = __builtin_amdgcn_mfma_f32_16x16x32_bf16(
                        afk[ks][kb], bfq[mi][ks], sc[kb], 0, 0, 0);

            float rmax = sc[0][0];
            #pragma unroll
            for (int kb = 0; kb < 4; kb++)
                #pragma unroll
                for (int r = 0; r < 4; r++)
                    rmax = fmaxf(rmax, sc[kb][r]);
            rmax = fmaxf(rmax, __shfl_xor(rmax, 16));
            rmax = fmaxf(rmax, __shfl_xor(rmax, 32));
            const float mnew = fmaxf(m2[mi], rmax * C2);
            alpha[mi] = EXP2(m2[mi] - mnew);
            m2[mi] = mnew;
            float ps = 0.f;
            #pragma unroll
            for (int kb = 0; kb < 4; kb++) {
                float p0 = EXP2(fmaf(sc[kb][0], C2, -mnew));
                float p1 = EXP2(fmaf(sc[kb][1], C2, -mnew));
                float p2 = EXP2(fmaf(sc[kb][2], C2, -mnew));
                float p3 = EXP2(fmaf(sc[kb][3], C2, -mnew));
                ps += (p0 + p1) + (p2 + p3);
                uint2 w;
                w.x = pack2_trunc(p0, p1);
                w.y = pack2_trunc(p2, p3);
                *reinterpret_cast<uint2*>(&myPs[(mi * 16 + rlo) * PSTR + kb * 16 + quad * 4]) = w;
            }
            l[mi] = l[mi] * alpha[mi] + ps;
        }

        // ---- rescale O (alpha at lane rlo = q-in-16) ----
        #pragma unroll
        for (int mi = 0; mi < 4; mi++)
            #pragma unroll
            for (int r = 0; r < 4; r++) {
                const float ar = __shfl(alpha[mi], (lane & 48) | (quad * 4 + r));
                #pragma unroll
                for (int db = 0; db < 4; db++)
                    o[mi][db][r] *= ar;
            }

        // ---- O += P V (Ps wave-private: no barrier needed) ----
        #pragma unroll
        for (int ks = 0; ks < 2; ks++) {
            s16x8 afp[4], bfv[4];
            #pragma unroll
            for (int mi = 0; mi < 4; mi++)
                afp[mi] = *reinterpret_cast<const s16x8*>(
                    &myPs[(mi * 16 + rlo) * PSTR + ks * 32 + quad * 8]);
            #pragma unroll
            for (int db = 0; db < 4; db++)
                bfv[db] = *reinterpret_cast<const s16x8*>(
                    &Vts[ks * 2048 + db * 512 + lane * 8]);
            #pragma unroll
            for (int mi = 0; mi < 4; mi++)
                #pragma unroll
                for (int db = 0; db < 4; db++)
                    o[mi][db] = __builtin_amdgcn_mfma_f32_16x16x32_bf16(
                        afp[mi], bfv[db], o[mi][db], 0, 0, 0);
        }
    }

    // ---- epilogue ----
    #pragma unroll
    for (int mi = 0; mi < 4; mi++) {
        float lf = l[mi];
        lf += __shfl_xor(lf, 16);
        lf += __shfl_xor(lf, 32);
        #pragma unroll
        for (int r = 0; r < 4; r++) {
            const float inv = 1.f / __shfl(lf, (lane & 48) | (quad * 4 + r));
            const long grow = qrow0 + wave * 64 + mi * 16 + quad * 4 + r;
            #pragma unroll
            for (int db = 0; db < 4; db++)
                C[grow * D_MODEL + colbase + db * 16 + rlo] = f2b(o[mi][db][r] * inv);
        }
    }
}

// ---------------- row LayerNorm in-place ----------------------------------------
__global__ __launch_bounds__(256)
void ln_inplace(float* __restrict__ Y, const float* __restrict__ gamma,
                const float* __restrict__ beta)
{
    const int row = blockIdx.x, t = threadIdx.x;
    float4 v = reinterpret_cast<float4*>(Y + (long)row * D_MODEL)[t];
    float s  = v.x + v.y + v.z + v.w;
    float ss = v.x * v.x + v.y * v.y + v.z * v.z + v.w * v.w;
    #pragma unroll
    for (int off = 32; off > 0; off >>= 1) {
        s  += __shfl_down(s, off, 64);
        ss += __shfl_down(ss, off, 64);
    }
    __shared__ float rs[4], rss[4];
    const int lane = t & 63, w = t >> 6;
    if (lane == 0) { rs[w] = s; rss[w] = ss; }
    __syncthreads();
    const float tot  = rs[0] + rs[1] + rs[2] + rs[3];
    const float tot2 = rss[0] + rss[1] + rss[2] + rss[3];
    const float mu   = tot * (1.f / D_MODEL);
    const float var  = tot2 * (1.f / D_MODEL) - mu * mu;
    const float rstd = rsqrtf(var + 1e-5f);
    const float4 g  = reinterpret_cast<const float4*>(gamma)[t];
    const float4 bb = reinterpret_cast<const float4*>(beta)[t];
    v.x = (v.x - mu) * rstd * g.x + bb.x;
    v.y = (v.y - mu) * rstd * g.y + bb.y;
    v.z = (v.z - mu) * rstd * g.z + bb.z;
    v.w = (v.w - mu) * rstd * g.w + bb.w;
    reinterpret_cast<float4*>(Y + (long)row * D_MODEL)[t] = v;
}

extern "C" void kernel_launch(void* const* d_in, const int* in_sizes, int n_in,
                              void* d_out, int out_size, void* d_ws, size_t ws_size,
                              hipStream_t stream)
{
    const float* x     = (const float*)d_in[0];
    const float* Wq    = (const float*)d_in[1];
    const float* bq    = (const float*)d_in[2];
    const float* Wk    = (const float*)d_in[3];
    const float* bk    = (const float*)d_in[4];
    const float* Wv    = (const float*)d_in[5];
    const float* bv    = (const float*)d_in[6];
    const float* Wo    = (const float*)d_in[7];
    const float* bo    = (const float*)d_in[8];
    const float* gamma = (const float*)d_in[9];
    const float* beta  = (const float*)d_in[10];
    float* out = (float*)d_out;

    u16* ws  = (u16*)d_ws;
    u16* xb  = ws;
    u16* Wqb = xb  + (size_t)MROWS * D_MODEL;
    u16* Wkb = Wqb + (size_t)D_MODEL * D_MODEL;
    u16* Wvb = Wkb + (size_t)D_MODEL * D_MODEL;
    u16* Wob = Wvb + (size_t)D_MODEL * D_MODEL;
    u16* Qb  = Wob + (size_t)D_MODEL * D_MODEL;
    u16* Kb  = Qb  + (size_t)MROWS * D_MODEL;
    u16* VtB = Kb  + (size_t)MROWS * D_MODEL;    // V^T in [b][h][d][s] layout
    u16* Cb  = VtB + (size_t)MROWS * D_MODEL;

    cvt_kernel<<<MROWS * D_MODEL / 1024, 256, 0, stream>>>(x,  xb,  MROWS * D_MODEL / 4);
    cvt_kernel<<<D_MODEL * D_MODEL / 1024, 256, 0, stream>>>(Wq, Wqb, D_MODEL * D_MODEL / 4);
    cvt_kernel<<<D_MODEL * D_MODEL / 1024, 256, 0, stream>>>(Wk, Wkb, D_MODEL * D_MODEL / 4);
    cvt_kernel<<<D_MODEL * D_MODEL / 1024, 256, 0, stream>>>(Wv, Wvb, D_MODEL * D_MODEL / 4);
    cvt_kernel<<<D_MODEL * D_MODEL / 1024, 256, 0, stream>>>(Wo, Wob, D_MODEL * D_MODEL / 4);

    dim3 gg(D_MODEL / BN, MROWS / BM);
    gemm_bf16_nt<<<gg, 256, 0, stream>>>(xb, Wqb, bq, nullptr, Qb, nullptr, nullptr, MROWS, D_MODEL, D_MODEL);
    gemm_bf16_nt<<<gg, 256, 0, stream>>>(xb, Wkb, bk, nullptr, Kb, nullptr, nullptr, MROWS, D_MODEL, D_MODEL);
    gemm_bf16_nt<<<gg, 256, 0, stream>>>(xb, Wvb, bv, nullptr, nullptr, nullptr, VtB, MROWS, D_MODEL, D_MODEL);

    flash_attn_mfma<<<dim3(SEQ / 256, NHEADS, BATCH), 256, 0, stream>>>(Qb, Kb, VtB, Cb);

    gemm_bf16_nt<<<gg, 256, 0, stream>>>(Cb, Wob, bo, x, nullptr, out, nullptr, MROWS, D_MODEL, D_MODEL);

    ln_inplace<<<MROWS, 256, 0, stream>>>(out, gamma, beta);
}

// Round 7
// 436.327 us; speedup vs baseline: 3.0214x; 1.0005x over previous
//
#include <hip/hip_runtime.h>

typedef unsigned short u16;
typedef unsigned int   u32;
typedef float f32x4 __attribute__((ext_vector_type(4)));
typedef short s16x8 __attribute__((ext_vector_type(8)));

#define D_MODEL 1024
#define NHEADS  16
#define DK      64
#define SEQ     2048
#define BATCH   4
#define MROWS   (BATCH * SEQ)   // 8192

// 0.125 (1/sqrt(dk)) * log2(e) — folded into Q projection epilogue
#define C2 0.18033688011112042f

#if __has_builtin(__builtin_amdgcn_exp2f)
#define EXP2(x) __builtin_amdgcn_exp2f(x)
#else
#define EXP2(x) exp2f(x)
#endif

// async global->LDS DMA, 16B per lane; dest = wave-uniform base + lane*16
#define GL16(gp, lp) __builtin_amdgcn_global_load_lds( \
    (const __attribute__((address_space(1))) u32*)(gp), \
    (__attribute__((address_space(3))) u32*)(lp), 16, 0, 0)

__device__ __forceinline__ u16 f2b(float f) {           // RNE
    u32 u = __builtin_bit_cast(u32, f);
    u32 r = (u + 0x7fffu + ((u >> 16) & 1u)) >> 16;
    return (u16)r;
}
// [a_hi16 | b_hi16] in one v_perm_b32 (truncating bf16 pack)
__device__ __forceinline__ u32 pack2_trunc(float a, float b) {
    return __builtin_amdgcn_perm(__builtin_bit_cast(u32, b),
                                 __builtin_bit_cast(u32, a), 0x07060302u);
}

// ---------------- fused fp32 -> bf16 conversion (x + 4 weights) -----------------
// regions (in float4 units): x: 2097152 | each W: 262144
__global__ __launch_bounds__(256)
void cvt_all(const float* __restrict__ x,  const float* __restrict__ wq,
             const float* __restrict__ wk, const float* __restrict__ wv,
             const float* __restrict__ wo,
             u16* __restrict__ xb, u16* __restrict__ wqb, u16* __restrict__ wkb,
             u16* __restrict__ wvb, u16* __restrict__ wob)
{
    const int i = blockIdx.x * 256 + threadIdx.x;
    const float* src; u16* dst; int off;
    if (i < 2097152) { src = x; dst = xb; off = i; }
    else {
        const int j = i - 2097152;
        const int w = j >> 18;
        off = j & 262143;
        if      (w == 0) { src = wq; dst = wqb; }
        else if (w == 1) { src = wk; dst = wkb; }
        else if (w == 2) { src = wv; dst = wvb; }
        else             { src = wo; dst = wob; }
    }
    const float4 v = reinterpret_cast<const float4*>(src)[off];
    u32 lo = (u32)f2b(v.x) | ((u32)f2b(v.y) << 16);
    u32 hi = (u32)f2b(v.z) | ((u32)f2b(v.w) << 16);
    reinterpret_cast<uint2*>(dst)[off] = make_uint2(lo, hi);
}

// ---------------- fused QKV bf16 MFMA NT GEMM, dbuf global_load_lds -------------
// grid (24, 64): blockIdx.x>>3 selects {Q,K,V}; n0=(bx&7)*128. LDS frag-major.
#define BM 128
#define BN 128
#define BK 32
#define KITER (D_MODEL / BK)

__global__ __launch_bounds__(256)
void gemm_qkv(const u16* __restrict__ A,
              const u16* __restrict__ Wq, const u16* __restrict__ Wk,
              const u16* __restrict__ Wv,
              const float* __restrict__ bq, const float* __restrict__ bk,
              const float* __restrict__ bv,
              u16* __restrict__ Qb, u16* __restrict__ Kb, u16* __restrict__ VtB)
{
    __shared__ __align__(16) u16 As[2][4096];
    __shared__ __align__(16) u16 Bs[2][4096];
    const int t    = threadIdx.x;
    const int lane = t & 63;
    const int wave = t >> 6;
    const int wr = wave >> 1, wc = wave & 1;
    const int sel = blockIdx.x >> 3;
    const int n0  = (blockIdx.x & 7) * BN;
    const int m0  = blockIdx.y * BM;
    const int quad = lane >> 4;
    const int rlo  = lane & 15;

    const u16* W = (sel == 0) ? Wq : (sel == 1) ? Wk : Wv;
    const float* bias = (sel == 0) ? bq : (sel == 1) ? bk : bv;

    const int srow0 = wave * 16 + rlo;
    const int scol  = quad * 8;
    const long aoff0 = (long)(m0 + srow0) * D_MODEL + scol;
    const long aoff1 = aoff0 + (long)64 * D_MODEL;
    const long boff0 = (long)(n0 + srow0) * D_MODEL + scol;
    const long boff1 = boff0 + (long)64 * D_MODEL;
    const int dst = wave * 512 + lane * 8;

    f32x4 acc[4][4];
    #pragma unroll
    for (int i = 0; i < 4; i++)
        #pragma unroll
        for (int j = 0; j < 4; j++)
            acc[i][j] = (f32x4){0.f, 0.f, 0.f, 0.f};

    // preload tile 0 -> buf 0
    GL16(A + aoff0, &As[0][dst]);
    GL16(A + aoff1, &As[0][dst + 2048]);
    GL16(W + boff0, &Bs[0][dst]);
    GL16(W + boff1, &Bs[0][dst + 2048]);

    for (int it = 0; it < KITER; it++) {
        const int cur = it & 1;
        __syncthreads();                       // drains DMA for buf cur
        if (it + 1 < KITER) {
            const int k0 = (it + 1) * BK;
            const int nxt = cur ^ 1;
            GL16(A + aoff0 + k0, &As[nxt][dst]);
            GL16(A + aoff1 + k0, &As[nxt][dst + 2048]);
            GL16(W + boff0 + k0, &Bs[nxt][dst]);
            GL16(W + boff1 + k0, &Bs[nxt][dst + 2048]);
        }
        s16x8 af[4], bf[4];
        #pragma unroll
        for (int i = 0; i < 4; i++)
            af[i] = *reinterpret_cast<const s16x8*>(&As[cur][(wr * 4 + i) * 512 + lane * 8]);
        #pragma unroll
        for (int j = 0; j < 4; j++)
            bf[j] = *reinterpret_cast<const s16x8*>(&Bs[cur][(wc * 4 + j) * 512 + lane * 8]);
        #pragma unroll
        for (int i = 0; i < 4; i++)
            #pragma unroll
            for (int j = 0; j < 4; j++)
                acc[i][j] = __builtin_amdgcn_mfma_f32_16x16x32_bf16(af[i], bf[j], acc[i][j], 0, 0, 0);
        __syncthreads();                       // all reads of buf cur done
    }

    if (sel == 2) {
        // V: transposed per-head epilogue VT[b][h][d][s]
        #pragma unroll
        for (int i = 0; i < 4; i++) {
            #pragma unroll
            for (int j = 0; j < 4; j++) {
                const int gm0 = m0 + wr * 64 + i * 16 + quad * 4;
                const int gn  = n0 + wc * 64 + j * 16 + rlo;
                const float bvx = bias[gn];
                const int bb = gm0 >> 11, s = gm0 & 2047;
                const int h = gn >> 6, d = gn & 63;
                uint2 w;
                w.x = (u32)f2b(acc[i][j][0] + bvx) | ((u32)f2b(acc[i][j][1] + bvx) << 16);
                w.y = (u32)f2b(acc[i][j][2] + bvx) | ((u32)f2b(acc[i][j][3] + bvx) << 16);
                *reinterpret_cast<uint2*>(VtB + ((long)((bb * 16 + h) * 64 + d)) * 2048 + s) = w;
            }
        }
    } else {
        u16* outp = (sel == 0) ? Qb : Kb;
        const float scale = (sel == 0) ? C2 : 1.0f;   // fold softmax scale into Q
        #pragma unroll
        for (int i = 0; i < 4; i++)
            #pragma unroll
            for (int j = 0; j < 4; j++)
                #pragma unroll
                for (int r = 0; r < 4; r++) {
                    const int gm = m0 + wr * 64 + i * 16 + quad * 4 + r;
                    const int gn = n0 + wc * 64 + j * 16 + rlo;
                    outp[(long)gm * D_MODEL + gn] = f2b((acc[i][j][r] + bias[gn]) * scale);
                }
    }
}

// ---------------- O-projection GEMM (+bias +residual, fp32 out), dbuf -----------
__global__ __launch_bounds__(256)
void gemm_o(const u16* __restrict__ A, const u16* __restrict__ W,
            const float* __restrict__ bias, const float* __restrict__ resid,
            float* __restrict__ outF)
{
    __shared__ __align__(16) u16 As[2][4096];
    __shared__ __align__(16) u16 Bs[2][4096];
    const int t    = threadIdx.x;
    const int lane = t & 63;
    const int wave = t >> 6;
    const int wr = wave >> 1, wc = wave & 1;
    const int n0  = blockIdx.x * BN;
    const int m0  = blockIdx.y * BM;
    const int quad = lane >> 4;
    const int rlo  = lane & 15;

    const int srow0 = wave * 16 + rlo;
    const int scol  = quad * 8;
    const long aoff0 = (long)(m0 + srow0) * D_MODEL + scol;
    const long aoff1 = aoff0 + (long)64 * D_MODEL;
    const long boff0 = (long)(n0 + srow0) * D_MODEL + scol;
    const long boff1 = boff0 + (long)64 * D_MODEL;
    const int dst = wave * 512 + lane * 8;

    f32x4 acc[4][4];
    #pragma unroll
    for (int i = 0; i < 4; i++)
        #pragma unroll
        for (int j = 0; j < 4; j++)
            acc[i][j] = (f32x4){0.f, 0.f, 0.f, 0.f};

    GL16(A + aoff0, &As[0][dst]);
    GL16(A + aoff1, &As[0][dst + 2048]);
    GL16(W + boff0, &Bs[0][dst]);
    GL16(W + boff1, &Bs[0][dst + 2048]);

    for (int it = 0; it < KITER; it++) {
        const int cur = it & 1;
        __syncthreads();
        if (it + 1 < KITER) {
            const int k0 = (it + 1) * BK;
            const int nxt = cur ^ 1;
            GL16(A + aoff0 + k0, &As[nxt][dst]);
            GL16(A + aoff1 + k0, &As[nxt][dst + 2048]);
            GL16(W + boff0 + k0, &Bs[nxt][dst]);
            GL16(W + boff1 + k0, &Bs[nxt][dst + 2048]);
        }
        s16x8 af[4], bf[4];
        #pragma unroll
        for (int i = 0; i < 4; i++)
            af[i] = *reinterpret_cast<const s16x8*>(&As[cur][(wr * 4 + i) * 512 + lane * 8]);
        #pragma unroll
        for (int j = 0; j < 4; j++)
            bf[j] = *reinterpret_cast<const s16x8*>(&Bs[cur][(wc * 4 + j) * 512 + lane * 8]);
        #pragma unroll
        for (int i = 0; i < 4; i++)
            #pragma unroll
            for (int j = 0; j < 4; j++)
                acc[i][j] = __builtin_amdgcn_mfma_f32_16x16x32_bf16(af[i], bf[j], acc[i][j], 0, 0, 0);
        __syncthreads();
    }

    #pragma unroll
    for (int i = 0; i < 4; i++)
        #pragma unroll
        for (int j = 0; j < 4; j++)
            #pragma unroll
            for (int r = 0; r < 4; r++) {
                const int gm = m0 + wr * 64 + i * 16 + quad * 4 + r;
                const int gn = n0 + wc * 64 + j * 16 + rlo;
                outF[(long)gm * D_MODEL + gn] =
                    acc[i][j][r] + bias[gn] + resid[(long)gm * D_MODEL + gn];
            }
}

// ---------------- flash attention: 256q block, 64q/wave, dbuf K/V staging -------
// Q pre-scaled by C2 (exp2 domain). l tracked as 5th ones-column of PV MFMA
// (auto-rescaled with O; column-replicated so epilogue needs no shuffles).
// LDS: Ps 4*64*72=18432 (Q [256][64] staged here first) | K 2x4096 | Vt 2x4096.
#define PSTR 72

__global__ __launch_bounds__(256)
void flash_attn_mfma(const u16* __restrict__ Qg, const u16* __restrict__ Kg,
                     const u16* __restrict__ VtG, u16* __restrict__ C)
{
    __shared__ __align__(16) u16 smem[34816];
    u16* KsB = &smem[18432];    // 2 x 4096
    u16* VtB = &smem[26624];    // 2 x 4096

    const int t    = threadIdx.x;
    const int lane = t & 63;
    const int wave = t >> 6;
    const int quad = lane >> 4;
    const int rlo  = lane & 15;
    const int qt = blockIdx.x, h = blockIdx.y, b = blockIdx.z;
    const long colbase = (long)h * DK;
    const long rowb    = (long)b * SEQ;
    const long qrow0   = rowb + (long)qt * 256;
    const u16* kg    = Kg + rowb * D_MODEL + colbase;
    const u16* vbase = VtG + (long)(b * 16 + h) * 64 * 2048;
    u16* myPs = &smem[wave * 64 * PSTR];

    const long koff = (long)(wave * 16 + rlo) * D_MODEL + quad * 8;
    const long voff = (long)(wave * 16 + rlo) * 2048 + quad * 8;
    const int  dkv  = wave * 512 + lane * 8;

    // ---- stage Q tile [256][64] + K/V tile 0 via DMA ----
    {
        const int qsrow = t >> 3;
        const int qscol = (t & 7) * 8;
        #pragma unroll
        for (int rr = 0; rr < 8; rr++)
            GL16(Qg + (qrow0 + rr * 32 + qsrow) * D_MODEL + colbase + qscol,
                 &smem[rr * 2048 + t * 8]);
    }
    GL16(kg + koff,          &KsB[dkv]);
    GL16(kg + koff + 32,     &KsB[dkv + 2048]);
    GL16(vbase + voff,       &VtB[dkv]);
    GL16(vbase + voff + 32,  &VtB[dkv + 2048]);
    __syncthreads();

    s16x8 bfq[4][2];
    #pragma unroll
    for (int mi = 0; mi < 4; mi++)
        #pragma unroll
        for (int ks = 0; ks < 2; ks++)
            bfq[mi][ks] = *reinterpret_cast<const s16x8*>(
                &smem[(wave * 64 + mi * 16 + rlo) * 64 + ks * 32 + quad * 8]);

    s16x8 ones;
    #pragma unroll
    for (int e = 0; e < 8; e++) ones[e] = (short)0x3F80;

    float m2[4] = {-INFINITY, -INFINITY, -INFINITY, -INFINITY};
    f32x4 o[4][4], o5[4];
    #pragma unroll
    for (int mi = 0; mi < 4; mi++) {
        o5[mi] = (f32x4){0.f, 0.f, 0.f, 0.f};
        #pragma unroll
        for (int db = 0; db < 4; db++)
            o[mi][db] = (f32x4){0.f, 0.f, 0.f, 0.f};
    }

    for (int kt = 0; kt < SEQ / 64; kt++) {
        const int cur = kt & 1;
        __syncthreads();   // drains DMA for buf cur; Q/P reads of prev iter done
        if (kt + 1 < SEQ / 64) {
            const long kv0 = (long)(kt + 1) * 64;
            const int nb = cur ^ 1;
            GL16(kg + kv0 * D_MODEL + koff,      &KsB[nb * 4096 + dkv]);
            GL16(kg + kv0 * D_MODEL + koff + 32, &KsB[nb * 4096 + dkv + 2048]);
            GL16(vbase + kv0 + voff,             &VtB[nb * 4096 + dkv]);
            GL16(vbase + kv0 + voff + 32,        &VtB[nb * 4096 + dkv + 2048]);
        }
        const u16* Ks  = &KsB[cur * 4096];
        const u16* Vts = &VtB[cur * 4096];

        // ---- K frags (lane-linear, conflict-free) ----
        s16x8 afk[2][4];
        #pragma unroll
        for (int ks = 0; ks < 2; ks++)
            #pragma unroll
            for (int kb = 0; kb < 4; kb++)
                afk[ks][kb] = *reinterpret_cast<const s16x8*>(
                    &Ks[ks * 2048 + kb * 512 + lane * 8]);

        // ---- per-mi: S^T = K Q^T, online softmax, P store ----
        float alpha[4];
        #pragma unroll
        for (int mi = 0; mi < 4; mi++) {
            f32x4 sc[4];
            #pragma unroll
            for (int kb = 0; kb < 4; kb++) sc[kb] = (f32x4){0.f, 0.f, 0.f, 0.f};
            #pragma unroll
            for (int ks = 0; ks < 2; ks++)
                #pragma unroll
                for (int kb = 0; kb < 4; kb++)
                    sc[kb] = __builtin_amdgcn_mfma_f32_16x16x32_bf16(
                        afk[ks][kb], bfq[mi][ks], sc[kb], 0, 0, 0);

            float rmax = sc[0][0];
            #pragma unroll
            for (int kb = 0; kb < 4; kb++)
                #pragma unroll
                for (int r = 0; r < 4; r++)
                    rmax = fmaxf(rmax, sc[kb][r]);
            rmax = fmaxf(rmax, __shfl_xor(rmax, 16));
            rmax = fmaxf(rmax, __shfl_xor(rmax, 32));
            const float mnew = fmaxf(m2[mi], rmax);
            alpha[mi] = EXP2(m2[mi] - mnew);
            m2[mi] = mnew;
            #pragma unroll
            for (int kb = 0; kb < 4; kb++) {
                float p0 = EXP2(sc[kb][0] - mnew);
                float p1 = EXP2(sc[kb][1] - mnew);
                float p2 = EXP2(sc[kb][2] - mnew);
                float p3 = EXP2(sc[kb][3] - mnew);
                uint2 w;
                w.x = pack2_trunc(p0, p1);
                w.y = pack2_trunc(p2, p3);
                *reinterpret_cast<uint2*>(&myPs[(mi * 16 + rlo) * PSTR + kb * 16 + quad * 4]) = w;
            }
        }

        // ---- rescale O and l-column by alpha ----
        #pragma unroll
        for (int mi = 0; mi < 4; mi++)
            #pragma unroll
            for (int r = 0; r < 4; r++) {
                const float ar = __shfl(alpha[mi], (lane & 48) | (quad * 4 + r));
                #pragma unroll
                for (int db = 0; db < 4; db++)
                    o[mi][db][r] *= ar;
                o5[mi][r] *= ar;
            }

        // ---- O += P V ; l += P 1 (5th column, same alpha chain) ----
        #pragma unroll
        for (int ks = 0; ks < 2; ks++) {
            s16x8 afp[4], bfv[4];
            #pragma unroll
            for (int mi = 0; mi < 4; mi++)
                afp[mi] = *reinterpret_cast<const s16x8*>(
                    &myPs[(mi * 16 + rlo) * PSTR + ks * 32 + quad * 8]);
            #pragma unroll
            for (int db = 0; db < 4; db++)
                bfv[db] = *reinterpret_cast<const s16x8*>(
                    &Vts[ks * 2048 + db * 512 + lane * 8]);
            #pragma unroll
            for (int mi = 0; mi < 4; mi++) {
                #pragma unroll
                for (int db = 0; db < 4; db++)
                    o[mi][db] = __builtin_amdgcn_mfma_f32_16x16x32_bf16(
                        afp[mi], bfv[db], o[mi][db], 0, 0, 0);
                o5[mi] = __builtin_amdgcn_mfma_f32_16x16x32_bf16(
                    afp[mi], ones, o5[mi], 0, 0, 0);
            }
        }
    }

    // ---- epilogue: O / l (l column-replicated -> no shuffles) ----
    #pragma unroll
    for (int mi = 0; mi < 4; mi++)
        #pragma unroll
        for (int r = 0; r < 4; r++) {
            const float inv = 1.f / o5[mi][r];
            const long grow = qrow0 + wave * 64 + mi * 16 + quad * 4 + r;
            #pragma unroll
            for (int db = 0; db < 4; db++)
                C[grow * D_MODEL + colbase + db * 16 + rlo] = f2b(o[mi][db][r] * inv);
        }
}

// ---------------- row LayerNorm in-place ----------------------------------------
__global__ __launch_bounds__(256)
void ln_inplace(float* __restrict__ Y, const float* __restrict__ gamma,
                const float* __restrict__ beta)
{
    const int row = blockIdx.x, t = threadIdx.x;
    float4 v = reinterpret_cast<float4*>(Y + (long)row * D_MODEL)[t];
    float s  = v.x + v.y + v.z + v.w;
    float ss = v.x * v.x + v.y * v.y + v.z * v.z + v.w * v.w;
    #pragma unroll
    for (int off = 32; off > 0; off >>= 1) {
        s  += __shfl_down(s, off, 64);
        ss += __shfl_down(ss, off, 64);
    }
    __shared__ float rs[4], rss[4];
    const int lane = t & 63, w = t >> 6;
    if (lane == 0) { rs[w] = s; rss[w] = ss; }
    __syncthreads();
    const float tot  = rs[0] + rs[1] + rs[2] + rs[3];
    const float tot2 = rss[0] + rss[1] + rss[2] + rss[3];
    const float mu   = tot * (1.f / D_MODEL);
    const float var  = tot2 * (1.f / D_MODEL) - mu * mu;
    const float rstd = rsqrtf(var + 1e-5f);
    const float4 g  = reinterpret_cast<const float4*>(gamma)[t];
    const float4 bb = reinterpret_cast<const float4*>(beta)[t];
    v.x = (v.x - mu) * rstd * g.x + bb.x;
    v.y = (v.y - mu) * rstd * g.y + bb.y;
    v.z = (v.z - mu) * rstd * g.z + bb.z;
    v.w = (v.w - mu) * rstd * g.w + bb.w;
    reinterpret_cast<float4*>(Y + (long)row * D_MODEL)[t] = v;
}

extern "C" void kernel_launch(void* const* d_in, const int* in_sizes, int n_in,
                              void* d_out, int out_size, void* d_ws, size_t ws_size,
                              hipStream_t stream)
{
    const float* x     = (const float*)d_in[0];
    const float* Wq    = (const float*)d_in[1];
    const float* bq    = (const float*)d_in[2];
    const float* Wk    = (const float*)d_in[3];
    const float* bk    = (const float*)d_in[4];
    const float* Wv    = (const float*)d_in[5];
    const float* bv    = (const float*)d_in[6];
    const float* Wo    = (const float*)d_in[7];
    const float* bo    = (const float*)d_in[8];
    const float* gamma = (const float*)d_in[9];
    const float* beta  = (const float*)d_in[10];
    float* out = (float*)d_out;

    u16* ws  = (u16*)d_ws;
    u16* xb  = ws;
    u16* Wqb = xb  + (size_t)MROWS * D_MODEL;
    u16* Wkb = Wqb + (size_t)D_MODEL * D_MODEL;
    u16* Wvb = Wkb + (size_t)D_MODEL * D_MODEL;
    u16* Wob = Wvb + (size_t)D_MODEL * D_MODEL;
    u16* Qb  = Wob + (size_t)D_MODEL * D_MODEL;
    u16* Kb  = Qb  + (size_t)MROWS * D_MODEL;
    u16* VtB = Kb  + (size_t)MROWS * D_MODEL;    // V^T in [b][h][d][s] layout
    u16* Cb  = VtB + (size_t)MROWS * D_MODEL;

    cvt_all<<<12288, 256, 0, stream>>>(x, Wq, Wk, Wv, Wo, xb, Wqb, Wkb, Wvb, Wob);

    gemm_qkv<<<dim3(24, 64), 256, 0, stream>>>(xb, Wqb, Wkb, Wvb, bq, bk, bv,
                                               Qb, Kb, VtB);

    flash_attn_mfma<<<dim3(SEQ / 256, NHEADS, BATCH), 256, 0, stream>>>(Qb, Kb, VtB, Cb);

    gemm_o<<<dim3(8, 64), 256, 0, stream>>>(Cb, Wob, bo, x, out);

    ln_inplace<<<MROWS, 256, 0, stream>>>(out, gamma, beta);
}

// Round 8
// 367.821 us; speedup vs baseline: 3.5841x; 1.1862x over previous
//
#include <hip/hip_runtime.h>

typedef unsigned short u16;
typedef unsigned int   u32;
typedef float f32x4 __attribute__((ext_vector_type(4)));
typedef short s16x8 __attribute__((ext_vector_type(8)));

#define D_MODEL 1024
#define NHEADS  16
#define DK      64
#define SEQ     2048
#define BATCH   4
#define MROWS   (BATCH * SEQ)   // 8192

// 0.125 (1/sqrt(dk)) * log2(e) — folded into Q projection epilogue
#define C2 0.18033688011112042f

#if __has_builtin(__builtin_amdgcn_exp2f)
#define EXP2(x) __builtin_amdgcn_exp2f(x)
#else
#define EXP2(x) exp2f(x)
#endif

// async global->LDS DMA, 16B per lane; dest = wave-uniform base + lane*16
#define GL16(gp, lp) __builtin_amdgcn_global_load_lds( \
    (const __attribute__((address_space(1))) u32*)(gp), \
    (__attribute__((address_space(3))) u32*)(lp), 16, 0, 0)

__device__ __forceinline__ u16 f2b(float f) {           // RNE
    u32 u = __builtin_bit_cast(u32, f);
    u32 r = (u + 0x7fffu + ((u >> 16) & 1u)) >> 16;
    return (u16)r;
}
// [a_hi16 | b_hi16] in one v_perm_b32 (truncating bf16 pack)
__device__ __forceinline__ u32 pack2_trunc(float a, float b) {
    return __builtin_amdgcn_perm(__builtin_bit_cast(u32, b),
                                 __builtin_bit_cast(u32, a), 0x07060302u);
}

// ---------------- fused fp32 -> bf16 conversion (x + 4 weights) -----------------
__global__ __launch_bounds__(256)
void cvt_all(const float* __restrict__ x,  const float* __restrict__ wq,
             const float* __restrict__ wk, const float* __restrict__ wv,
             const float* __restrict__ wo,
             u16* __restrict__ xb, u16* __restrict__ wqb, u16* __restrict__ wkb,
             u16* __restrict__ wvb, u16* __restrict__ wob)
{
    const int i = blockIdx.x * 256 + threadIdx.x;
    const float* src; u16* dst; int off;
    if (i < 2097152) { src = x; dst = xb; off = i; }
    else {
        const int j = i - 2097152;
        const int w = j >> 18;
        off = j & 262143;
        if      (w == 0) { src = wq; dst = wqb; }
        else if (w == 1) { src = wk; dst = wkb; }
        else if (w == 2) { src = wv; dst = wvb; }
        else             { src = wo; dst = wob; }
    }
    const float4 v = reinterpret_cast<const float4*>(src)[off];
    u32 lo = (u32)f2b(v.x) | ((u32)f2b(v.y) << 16);
    u32 hi = (u32)f2b(v.z) | ((u32)f2b(v.w) << 16);
    reinterpret_cast<uint2*>(dst)[off] = make_uint2(lo, hi);
}

// ---------------- fused QKV bf16 MFMA NT GEMM, dbuf, 1 barrier/iter -------------
#define BM 128
#define BN 128
#define BK 32
#define KITER (D_MODEL / BK)

__global__ __launch_bounds__(256, 3)
void gemm_qkv(const u16* __restrict__ A,
              const u16* __restrict__ Wq, const u16* __restrict__ Wk,
              const u16* __restrict__ Wv,
              const float* __restrict__ bq, const float* __restrict__ bk,
              const float* __restrict__ bv,
              u16* __restrict__ Qb, u16* __restrict__ Kb, u16* __restrict__ VtB)
{
    __shared__ __align__(16) u16 As[2][4096];
    __shared__ __align__(16) u16 Bs[2][4096];
    const int t    = threadIdx.x;
    const int lane = t & 63;
    const int wave = t >> 6;
    const int wr = wave >> 1, wc = wave & 1;
    const int sel = blockIdx.x >> 3;
    const int n0  = (blockIdx.x & 7) * BN;
    const int m0  = blockIdx.y * BM;
    const int quad = lane >> 4;
    const int rlo  = lane & 15;

    const u16* W = (sel == 0) ? Wq : (sel == 1) ? Wk : Wv;
    const float* bias = (sel == 0) ? bq : (sel == 1) ? bk : bv;

    const int srow0 = wave * 16 + rlo;
    const int scol  = quad * 8;
    const long aoff0 = (long)(m0 + srow0) * D_MODEL + scol;
    const long aoff1 = aoff0 + (long)64 * D_MODEL;
    const long boff0 = (long)(n0 + srow0) * D_MODEL + scol;
    const long boff1 = boff0 + (long)64 * D_MODEL;
    const int dst = wave * 512 + lane * 8;

    f32x4 acc[4][4];
    #pragma unroll
    for (int i = 0; i < 4; i++)
        #pragma unroll
        for (int j = 0; j < 4; j++)
            acc[i][j] = (f32x4){0.f, 0.f, 0.f, 0.f};

    GL16(A + aoff0, &As[0][dst]);
    GL16(A + aoff1, &As[0][dst + 2048]);
    GL16(W + boff0, &Bs[0][dst]);
    GL16(W + boff1, &Bs[0][dst + 2048]);

    for (int it = 0; it < KITER; it++) {
        const int cur = it & 1;
        __syncthreads();                       // drains DMA for buf cur
        if (it + 1 < KITER) {
            const int k0 = (it + 1) * BK;
            const int nxt = cur ^ 1;
            GL16(A + aoff0 + k0, &As[nxt][dst]);
            GL16(A + aoff1 + k0, &As[nxt][dst + 2048]);
            GL16(W + boff0 + k0, &Bs[nxt][dst]);
            GL16(W + boff1 + k0, &Bs[nxt][dst + 2048]);
        }
        s16x8 af[4], bf[4];
        #pragma unroll
        for (int i = 0; i < 4; i++)
            af[i] = *reinterpret_cast<const s16x8*>(&As[cur][(wr * 4 + i) * 512 + lane * 8]);
        #pragma unroll
        for (int j = 0; j < 4; j++)
            bf[j] = *reinterpret_cast<const s16x8*>(&Bs[cur][(wc * 4 + j) * 512 + lane * 8]);
        #pragma unroll
        for (int i = 0; i < 4; i++)
            #pragma unroll
            for (int j = 0; j < 4; j++)
                acc[i][j] = __builtin_amdgcn_mfma_f32_16x16x32_bf16(af[i], bf[j], acc[i][j], 0, 0, 0);
        // no bottom barrier: frag reads of buf cur are drained (lgkmcnt before
        // MFMA) before any wave can reach the next top barrier and DMA into cur.
    }

    if (sel == 2) {
        // V: transposed per-head epilogue VT[b][h][d][s]
        #pragma unroll
        for (int i = 0; i < 4; i++) {
            #pragma unroll
            for (int j = 0; j < 4; j++) {
                const int gm0 = m0 + wr * 64 + i * 16 + quad * 4;
                const int gn  = n0 + wc * 64 + j * 16 + rlo;
                const float bvx = bias[gn];
                const int bb = gm0 >> 11, s = gm0 & 2047;
                const int h = gn >> 6, d = gn & 63;
                uint2 w;
                w.x = (u32)f2b(acc[i][j][0] + bvx) | ((u32)f2b(acc[i][j][1] + bvx) << 16);
                w.y = (u32)f2b(acc[i][j][2] + bvx) | ((u32)f2b(acc[i][j][3] + bvx) << 16);
                *reinterpret_cast<uint2*>(VtB + ((long)((bb * 16 + h) * 64 + d)) * 2048 + s) = w;
            }
        }
    } else {
        u16* outp = (sel == 0) ? Qb : Kb;
        const float scale = (sel == 0) ? C2 : 1.0f;   // fold softmax scale into Q
        #pragma unroll
        for (int i = 0; i < 4; i++)
            #pragma unroll
            for (int j = 0; j < 4; j++)
                #pragma unroll
                for (int r = 0; r < 4; r++) {
                    const int gm = m0 + wr * 64 + i * 16 + quad * 4 + r;
                    const int gn = n0 + wc * 64 + j * 16 + rlo;
                    outp[(long)gm * D_MODEL + gn] = f2b((acc[i][j][r] + bias[gn]) * scale);
                }
    }
}

// ---------------- O-projection GEMM (+bias +residual, fp32 out), dbuf -----------
__global__ __launch_bounds__(256, 3)
void gemm_o(const u16* __restrict__ A, const u16* __restrict__ W,
            const float* __restrict__ bias, const float* __restrict__ resid,
            float* __restrict__ outF)
{
    __shared__ __align__(16) u16 As[2][4096];
    __shared__ __align__(16) u16 Bs[2][4096];
    const int t    = threadIdx.x;
    const int lane = t & 63;
    const int wave = t >> 6;
    const int wr = wave >> 1, wc = wave & 1;
    const int n0  = blockIdx.x * BN;
    const int m0  = blockIdx.y * BM;
    const int quad = lane >> 4;
    const int rlo  = lane & 15;

    const int srow0 = wave * 16 + rlo;
    const int scol  = quad * 8;
    const long aoff0 = (long)(m0 + srow0) * D_MODEL + scol;
    const long aoff1 = aoff0 + (long)64 * D_MODEL;
    const long boff0 = (long)(n0 + srow0) * D_MODEL + scol;
    const long boff1 = boff0 + (long)64 * D_MODEL;
    const int dst = wave * 512 + lane * 8;

    f32x4 acc[4][4];
    #pragma unroll
    for (int i = 0; i < 4; i++)
        #pragma unroll
        for (int j = 0; j < 4; j++)
            acc[i][j] = (f32x4){0.f, 0.f, 0.f, 0.f};

    GL16(A + aoff0, &As[0][dst]);
    GL16(A + aoff1, &As[0][dst + 2048]);
    GL16(W + boff0, &Bs[0][dst]);
    GL16(W + boff1, &Bs[0][dst + 2048]);

    for (int it = 0; it < KITER; it++) {
        const int cur = it & 1;
        __syncthreads();
        if (it + 1 < KITER) {
            const int k0 = (it + 1) * BK;
            const int nxt = cur ^ 1;
            GL16(A + aoff0 + k0, &As[nxt][dst]);
            GL16(A + aoff1 + k0, &As[nxt][dst + 2048]);
            GL16(W + boff0 + k0, &Bs[nxt][dst]);
            GL16(W + boff1 + k0, &Bs[nxt][dst + 2048]);
        }
        s16x8 af[4], bf[4];
        #pragma unroll
        for (int i = 0; i < 4; i++)
            af[i] = *reinterpret_cast<const s16x8*>(&As[cur][(wr * 4 + i) * 512 + lane * 8]);
        #pragma unroll
        for (int j = 0; j < 4; j++)
            bf[j] = *reinterpret_cast<const s16x8*>(&Bs[cur][(wc * 4 + j) * 512 + lane * 8]);
        #pragma unroll
        for (int i = 0; i < 4; i++)
            #pragma unroll
            for (int j = 0; j < 4; j++)
                acc[i][j] = __builtin_amdgcn_mfma_f32_16x16x32_bf16(af[i], bf[j], acc[i][j], 0, 0, 0);
    }

    #pragma unroll
    for (int i = 0; i < 4; i++)
        #pragma unroll
        for (int j = 0; j < 4; j++)
            #pragma unroll
            for (int r = 0; r < 4; r++) {
                const int gm = m0 + wr * 64 + i * 16 + quad * 4 + r;
                const int gn = n0 + wc * 64 + j * 16 + rlo;
                outF[(long)gm * D_MODEL + gn] =
                    acc[i][j][r] + bias[gn] + resid[(long)gm * D_MODEL + gn];
            }
}

// ---------------- flash attention: 128q block, 4 waves x 32q, P-streaming -------
// Q frags direct from global (no LDS stage). Per-mi P streaming: P written and
// consumed one 16-row block at a time in a wave-private LDS region (in-wave
// lgkmcnt ordering only, no barrier). Dbuf K/V via global_load_lds, 1 barrier
// per kv-tile. LDS = 4*1152 (Ps) + 2*4096 (K) + 2*4096 (Vt) = 20992 u16 = 41 KB
// -> 3 blocks/CU; grid = 16*16*4 = 1024 blocks (4/CU available).
#define PSTR 72

__global__ __launch_bounds__(256, 3)
void flash_attn_mfma(const u16* __restrict__ Qg, const u16* __restrict__ Kg,
                     const u16* __restrict__ VtG, u16* __restrict__ C)
{
    __shared__ __align__(16) u16 smem[20992];
    u16* KsB   = &smem[4608];     // 2 x 4096
    u16* VtBuf = &smem[12800];    // 2 x 4096

    const int t    = threadIdx.x;
    const int lane = t & 63;
    const int wave = t >> 6;
    const int quad = lane >> 4;
    const int rlo  = lane & 15;
    const int qt = blockIdx.x, h = blockIdx.y, b = blockIdx.z;
    const long colbase = (long)h * DK;
    const long rowb    = (long)b * SEQ;
    const long qrow0   = rowb + (long)qt * 128;
    const u16* kg    = Kg + rowb * D_MODEL + colbase;
    const u16* vbase = VtG + (long)(b * 16 + h) * 64 * 2048;
    u16* myPs = &smem[wave * 1152];   // 16 rows x PSTR, wave-private

    const long koff = (long)(wave * 16 + rlo) * D_MODEL + quad * 8;
    const long voff = (long)(wave * 16 + rlo) * 2048 + quad * 8;
    const int  dkv  = wave * 512 + lane * 8;

    // ---- K/V tile 0 DMA ----
    GL16(kg + koff,         &KsB[dkv]);
    GL16(kg + koff + 32,    &KsB[dkv + 2048]);
    GL16(vbase + voff,      &VtBuf[dkv]);
    GL16(vbase + voff + 32, &VtBuf[dkv + 2048]);

    // ---- Q frags direct from global (Q pre-scaled by C2 in projection) ----
    s16x8 bfq[2][2];
    #pragma unroll
    for (int mi = 0; mi < 2; mi++)
        #pragma unroll
        for (int ks = 0; ks < 2; ks++)
            bfq[mi][ks] = *reinterpret_cast<const s16x8*>(
                Qg + (qrow0 + wave * 32 + mi * 16 + rlo) * D_MODEL +
                colbase + ks * 32 + quad * 8);

    s16x8 ones;
    #pragma unroll
    for (int e = 0; e < 8; e++) ones[e] = (short)0x3F80;

    float m2[2] = {-INFINITY, -INFINITY};
    f32x4 o[2][4], o5[2];
    #pragma unroll
    for (int mi = 0; mi < 2; mi++) {
        o5[mi] = (f32x4){0.f, 0.f, 0.f, 0.f};
        #pragma unroll
        for (int db = 0; db < 4; db++)
            o[mi][db] = (f32x4){0.f, 0.f, 0.f, 0.f};
    }

    for (int kt = 0; kt < SEQ / 64; kt++) {
        const int cur = kt & 1;
        __syncthreads();   // drains DMA into buf cur (issued last iter / preload)
        if (kt + 1 < SEQ / 64) {
            const long kv0 = (long)(kt + 1) * 64;
            const int nb = cur ^ 1;
            GL16(kg + kv0 * D_MODEL + koff,      &KsB[nb * 4096 + dkv]);
            GL16(kg + kv0 * D_MODEL + koff + 32, &KsB[nb * 4096 + dkv + 2048]);
            GL16(vbase + kv0 + voff,             &VtBuf[nb * 4096 + dkv]);
            GL16(vbase + kv0 + voff + 32,        &VtBuf[nb * 4096 + dkv + 2048]);
        }
        const u16* Ks  = &KsB[cur * 4096];
        const u16* Vts = &VtBuf[cur * 4096];

        // ---- K and V frags (lane-linear, conflict-free b128) ----
        s16x8 afk[2][4], bfv[4][2];
        #pragma unroll
        for (int ks = 0; ks < 2; ks++)
            #pragma unroll
            for (int kb = 0; kb < 4; kb++)
                afk[ks][kb] = *reinterpret_cast<const s16x8*>(
                    &Ks[ks * 2048 + kb * 512 + lane * 8]);
        #pragma unroll
        for (int db = 0; db < 4; db++)
            #pragma unroll
            for (int ks = 0; ks < 2; ks++)
                bfv[db][ks] = *reinterpret_cast<const s16x8*>(
                    &Vts[ks * 2048 + db * 512 + lane * 8]);

        // ---- per-mi: S^T -> softmax -> P stream -> PV ----
        #pragma unroll
        for (int mi = 0; mi < 2; mi++) {
            f32x4 sc[4];
            #pragma unroll
            for (int kb = 0; kb < 4; kb++) sc[kb] = (f32x4){0.f, 0.f, 0.f, 0.f};
            #pragma unroll
            for (int ks = 0; ks < 2; ks++)
                #pragma unroll
                for (int kb = 0; kb < 4; kb++)
                    sc[kb] = __builtin_amdgcn_mfma_f32_16x16x32_bf16(
                        afk[ks][kb], bfq[mi][ks], sc[kb], 0, 0, 0);

            float rmax = sc[0][0];
            #pragma unroll
            for (int kb = 0; kb < 4; kb++)
                #pragma unroll
                for (int r = 0; r < 4; r++)
                    rmax = fmaxf(rmax, sc[kb][r]);
            rmax = fmaxf(rmax, __shfl_xor(rmax, 16));
            rmax = fmaxf(rmax, __shfl_xor(rmax, 32));
            const float mnew = fmaxf(m2[mi], rmax);
            const float alpha = EXP2(m2[mi] - mnew);
            m2[mi] = mnew;
            #pragma unroll
            for (int kb = 0; kb < 4; kb++) {
                float p0 = EXP2(sc[kb][0] - mnew);
                float p1 = EXP2(sc[kb][1] - mnew);
                float p2 = EXP2(sc[kb][2] - mnew);
                float p3 = EXP2(sc[kb][3] - mnew);
                uint2 w;
                w.x = pack2_trunc(p0, p1);
                w.y = pack2_trunc(p2, p3);
                *reinterpret_cast<uint2*>(&myPs[rlo * PSTR + kb * 16 + quad * 4]) = w;
            }

            // read A-frags of P (in-wave ds ordering; no barrier)
            s16x8 afp[2];
            #pragma unroll
            for (int ks = 0; ks < 2; ks++)
                afp[ks] = *reinterpret_cast<const s16x8*>(
                    &myPs[rlo * PSTR + ks * 32 + quad * 8]);

            // rescale O/l by alpha (broadcast from lane with rlo = q)
            #pragma unroll
            for (int r = 0; r < 4; r++) {
                const float ar = __shfl(alpha, (lane & 48) | (quad * 4 + r));
                #pragma unroll
                for (int db = 0; db < 4; db++)
                    o[mi][db][r] *= ar;
                o5[mi][r] *= ar;
            }

            // PV + ones column
            #pragma unroll
            for (int ks = 0; ks < 2; ks++) {
                #pragma unroll
                for (int db = 0; db < 4; db++)
                    o[mi][db] = __builtin_amdgcn_mfma_f32_16x16x32_bf16(
                        afp[ks], bfv[db][ks], o[mi][db], 0, 0, 0);
                o5[mi] = __builtin_amdgcn_mfma_f32_16x16x32_bf16(
                    afp[ks], ones, o5[mi], 0, 0, 0);
            }
        }
    }

    // ---- epilogue: O / l (l column-replicated -> no shuffles) ----
    #pragma unroll
    for (int mi = 0; mi < 2; mi++)
        #pragma unroll
        for (int r = 0; r < 4; r++) {
            const float inv = 1.f / o5[mi][r];
            const long grow = qrow0 + wave * 32 + mi * 16 + quad * 4 + r;
            #pragma unroll
            for (int db = 0; db < 4; db++)
                C[grow * D_MODEL + colbase + db * 16 + rlo] = f2b(o[mi][db][r] * inv);
        }
}

// ---------------- row LayerNorm in-place ----------------------------------------
__global__ __launch_bounds__(256)
void ln_inplace(float* __restrict__ Y, const float* __restrict__ gamma,
                const float* __restrict__ beta)
{
    const int row = blockIdx.x, t = threadIdx.x;
    float4 v = reinterpret_cast<float4*>(Y + (long)row * D_MODEL)[t];
    float s  = v.x + v.y + v.z + v.w;
    float ss = v.x * v.x + v.y * v.y + v.z * v.z + v.w * v.w;
    #pragma unroll
    for (int off = 32; off > 0; off >>= 1) {
        s  += __shfl_down(s, off, 64);
        ss += __shfl_down(ss, off, 64);
    }
    __shared__ float rs[4], rss[4];
    const int lane = t & 63, w = t >> 6;
    if (lane == 0) { rs[w] = s; rss[w] = ss; }
    __syncthreads();
    const float tot  = rs[0] + rs[1] + rs[2] + rs[3];
    const float tot2 = rss[0] + rss[1] + rss[2] + rss[3];
    const float mu   = tot * (1.f / D_MODEL);
    const float var  = tot2 * (1.f / D_MODEL) - mu * mu;
    const float rstd = rsqrtf(var + 1e-5f);
    const float4 g  = reinterpret_cast<const float4*>(gamma)[t];
    const float4 bb = reinterpret_cast<const float4*>(beta)[t];
    v.x = (v.x - mu) * rstd * g.x + bb.x;
    v.y = (v.y - mu) * rstd * g.y + bb.y;
    v.z = (v.z - mu) * rstd * g.z + bb.z;
    v.w = (v.w - mu) * rstd * g.w + bb.w;
    reinterpret_cast<float4*>(Y + (long)row * D_MODEL)[t] = v;
}

extern "C" void kernel_launch(void* const* d_in, const int* in_sizes, int n_in,
                              void* d_out, int out_size, void* d_ws, size_t ws_size,
                              hipStream_t stream)
{
    const float* x     = (const float*)d_in[0];
    const float* Wq    = (const float*)d_in[1];
    const float* bq    = (const float*)d_in[2];
    const float* Wk    = (const float*)d_in[3];
    const float* bk    = (const float*)d_in[4];
    const float* Wv    = (const float*)d_in[5];
    const float* bv    = (const float*)d_in[6];
    const float* Wo    = (const float*)d_in[7];
    const float* bo    = (const float*)d_in[8];
    const float* gamma = (const float*)d_in[9];
    const float* beta  = (const float*)d_in[10];
    float* out = (float*)d_out;

    u16* ws  = (u16*)d_ws;
    u16* xb  = ws;
    u16* Wqb = xb  + (size_t)MROWS * D_MODEL;
    u16* Wkb = Wqb + (size_t)D_MODEL * D_MODEL;
    u16* Wvb = Wkb + (size_t)D_MODEL * D_MODEL;
    u16* Wob = Wvb + (size_t)D_MODEL * D_MODEL;
    u16* Qb  = Wob + (size_t)D_MODEL * D_MODEL;
    u16* Kb  = Qb  + (size_t)MROWS * D_MODEL;
    u16* VtB = Kb  + (size_t)MROWS * D_MODEL;    // V^T in [b][h][d][s] layout
    u16* Cb  = VtB + (size_t)MROWS * D_MODEL;

    cvt_all<<<12288, 256, 0, stream>>>(x, Wq, Wk, Wv, Wo, xb, Wqb, Wkb, Wvb, Wob);

    gemm_qkv<<<dim3(24, 64), 256, 0, stream>>>(xb, Wqb, Wkb, Wvb, bq, bk, bv,
                                               Qb, Kb, VtB);

    flash_attn_mfma<<<dim3(SEQ / 128, NHEADS, BATCH), 256, 0, stream>>>(Qb, Kb, VtB, Cb);

    gemm_o<<<dim3(8, 64), 256, 0, stream>>>(Cb, Wob, bo, x, out);

    ln_inplace<<<MROWS, 256, 0, stream>>>(out, gamma, beta);
}

// Round 9
// 361.942 us; speedup vs baseline: 3.6423x; 1.0162x over previous
//
#include <hip/hip_runtime.h>

typedef unsigned short u16;
typedef unsigned int   u32;
typedef float f32x4 __attribute__((ext_vector_type(4)));
typedef short s16x8 __attribute__((ext_vector_type(8)));

#define D_MODEL 1024
#define NHEADS  16
#define DK      64
#define SEQ     2048
#define BATCH   4
#define MROWS   (BATCH * SEQ)   // 8192

// 0.125 (1/sqrt(dk)) * log2(e) — folded into Q projection epilogue
#define C2 0.18033688011112042f

#if __has_builtin(__builtin_amdgcn_exp2f)
#define EXP2(x) __builtin_amdgcn_exp2f(x)
#else
#define EXP2(x) exp2f(x)
#endif

// async global->LDS DMA, 16B per lane; dest = wave-uniform base + lane*16
#define GL16(gp, lp) __builtin_amdgcn_global_load_lds( \
    (const __attribute__((address_space(1))) u32*)(gp), \
    (__attribute__((address_space(3))) u32*)(lp), 16, 0, 0)

__device__ __forceinline__ u16 f2b(float f) {           // RNE
    u32 u = __builtin_bit_cast(u32, f);
    u32 r = (u + 0x7fffu + ((u >> 16) & 1u)) >> 16;
    return (u16)r;
}
// [a_hi16 | b_hi16] in one v_perm_b32 (truncating bf16 pack)
__device__ __forceinline__ u32 pack2_trunc(float a, float b) {
    return __builtin_amdgcn_perm(__builtin_bit_cast(u32, b),
                                 __builtin_bit_cast(u32, a), 0x07060302u);
}

// ---------------- fused fp32 -> bf16 conversion (x + 4 weights) -----------------
__global__ __launch_bounds__(256)
void cvt_all(const float* __restrict__ x,  const float* __restrict__ wq,
             const float* __restrict__ wk, const float* __restrict__ wv,
             const float* __restrict__ wo,
             u16* __restrict__ xb, u16* __restrict__ wqb, u16* __restrict__ wkb,
             u16* __restrict__ wvb, u16* __restrict__ wob)
{
    const int i = blockIdx.x * 256 + threadIdx.x;
    const float* src; u16* dst; int off;
    if (i < 2097152) { src = x; dst = xb; off = i; }
    else {
        const int j = i - 2097152;
        const int w = j >> 18;
        off = j & 262143;
        if      (w == 0) { src = wq; dst = wqb; }
        else if (w == 1) { src = wk; dst = wkb; }
        else if (w == 2) { src = wv; dst = wvb; }
        else             { src = wo; dst = wob; }
    }
    const float4 v = reinterpret_cast<const float4*>(src)[off];
    u32 lo = (u32)f2b(v.x) | ((u32)f2b(v.y) << 16);
    u32 hi = (u32)f2b(v.z) | ((u32)f2b(v.w) << 16);
    reinterpret_cast<uint2*>(dst)[off] = make_uint2(lo, hi);
}

// ---------------- fused QKV GEMM: 512 threads, BM=256 x BN=128, dbuf ------------
// 8 waves, wave grid 4m x 2n, each wave 64x64. LDS frag-major:
// A: 16 blocks of 512 u16 (block j = rows j*16+rlo, k=quad*8); B: 8 blocks.
// Staging: wave w writes A blocks {w, 8+w}, B block {w} -> 3 GL16/thread/iter.
// dbuf 2 x (16K + 8K) = 48 KB. One barrier per K-iter.
#define QBM 256
#define QBN 128
#define BK 32
#define KITER (D_MODEL / BK)

__global__ __launch_bounds__(512, 4)
void gemm_qkv(const u16* __restrict__ A,
              const u16* __restrict__ Wq, const u16* __restrict__ Wk,
              const u16* __restrict__ Wv,
              const float* __restrict__ bq, const float* __restrict__ bk,
              const float* __restrict__ bv,
              u16* __restrict__ Qb, u16* __restrict__ Kb, u16* __restrict__ VtB)
{
    __shared__ __align__(16) u16 As[2][8192];
    __shared__ __align__(16) u16 Bs[2][4096];
    const int t    = threadIdx.x;
    const int lane = t & 63;
    const int w    = t >> 6;             // 0..7
    const int wm = w >> 1, wn = w & 1;
    const int sel = blockIdx.x >> 3;
    const int n0  = (blockIdx.x & 7) * QBN;
    const int m0  = blockIdx.y * QBM;
    const int quad = lane >> 4;
    const int rlo  = lane & 15;

    const u16* W = (sel == 0) ? Wq : (sel == 1) ? Wk : Wv;
    const float* bias = (sel == 0) ? bq : (sel == 1) ? bk : bv;

    const int srow = w * 16 + rlo;
    const long aoff0 = (long)(m0 + srow) * D_MODEL + quad * 8;
    const long aoff1 = aoff0 + (long)128 * D_MODEL;
    const long boff  = (long)(n0 + srow) * D_MODEL + quad * 8;
    const int dstw = w * 512 + lane * 8;

    f32x4 acc[4][4];
    #pragma unroll
    for (int i = 0; i < 4; i++)
        #pragma unroll
        for (int j = 0; j < 4; j++)
            acc[i][j] = (f32x4){0.f, 0.f, 0.f, 0.f};

    GL16(A + aoff0, &As[0][dstw]);
    GL16(A + aoff1, &As[0][dstw + 4096]);
    GL16(W + boff,  &Bs[0][dstw]);

    for (int it = 0; it < KITER; it++) {
        const int cur = it & 1;
        __syncthreads();                       // drains DMA for buf cur
        if (it + 1 < KITER) {
            const int k0 = (it + 1) * BK;
            const int nxt = cur ^ 1;
            GL16(A + aoff0 + k0, &As[nxt][dstw]);
            GL16(A + aoff1 + k0, &As[nxt][dstw + 4096]);
            GL16(W + boff + k0,  &Bs[nxt][dstw]);
        }
        s16x8 af[4], bf[4];
        #pragma unroll
        for (int i = 0; i < 4; i++)
            af[i] = *reinterpret_cast<const s16x8*>(&As[cur][(wm * 4 + i) * 512 + lane * 8]);
        #pragma unroll
        for (int j = 0; j < 4; j++)
            bf[j] = *reinterpret_cast<const s16x8*>(&Bs[cur][(wn * 4 + j) * 512 + lane * 8]);
        #pragma unroll
        for (int i = 0; i < 4; i++)
            #pragma unroll
            for (int j = 0; j < 4; j++)
                acc[i][j] = __builtin_amdgcn_mfma_f32_16x16x32_bf16(af[i], bf[j], acc[i][j], 0, 0, 0);
        // no bottom barrier: reads of buf cur drain before any wave reaches the
        // next top barrier and DMAs into cur (one-barrier dbuf invariant).
    }

    if (sel == 2) {
        // V: transposed per-head epilogue VT[b][h][d][s]
        #pragma unroll
        for (int i = 0; i < 4; i++) {
            #pragma unroll
            for (int j = 0; j < 4; j++) {
                const int gm0 = m0 + wm * 64 + i * 16 + quad * 4;
                const int gn  = n0 + wn * 64 + j * 16 + rlo;
                const float bvx = bias[gn];
                const int bb = gm0 >> 11, s = gm0 & 2047;
                const int h = gn >> 6, d = gn & 63;
                uint2 wv2;
                wv2.x = (u32)f2b(acc[i][j][0] + bvx) | ((u32)f2b(acc[i][j][1] + bvx) << 16);
                wv2.y = (u32)f2b(acc[i][j][2] + bvx) | ((u32)f2b(acc[i][j][3] + bvx) << 16);
                *reinterpret_cast<uint2*>(VtB + ((long)((bb * 16 + h) * 64 + d)) * 2048 + s) = wv2;
            }
        }
    } else {
        u16* outp = (sel == 0) ? Qb : Kb;
        const float scale = (sel == 0) ? C2 : 1.0f;   // fold softmax scale into Q
        #pragma unroll
        for (int i = 0; i < 4; i++)
            #pragma unroll
            for (int j = 0; j < 4; j++)
                #pragma unroll
                for (int r = 0; r < 4; r++) {
                    const int gm = m0 + wm * 64 + i * 16 + quad * 4 + r;
                    const int gn = n0 + wn * 64 + j * 16 + rlo;
                    outp[(long)gm * D_MODEL + gn] = f2b((acc[i][j][r] + bias[gn]) * scale);
                }
    }
}

// ---------------- O-projection GEMM (+bias +residual, fp32 out), dbuf -----------
#define BM 128
#define BN 128

__global__ __launch_bounds__(256, 3)
void gemm_o(const u16* __restrict__ A, const u16* __restrict__ W,
            const float* __restrict__ bias, const float* __restrict__ resid,
            float* __restrict__ outF)
{
    __shared__ __align__(16) u16 As[2][4096];
    __shared__ __align__(16) u16 Bs[2][4096];
    const int t    = threadIdx.x;
    const int lane = t & 63;
    const int wave = t >> 6;
    const int wr = wave >> 1, wc = wave & 1;
    const int n0  = blockIdx.x * BN;
    const int m0  = blockIdx.y * BM;
    const int quad = lane >> 4;
    const int rlo  = lane & 15;

    const int srow0 = wave * 16 + rlo;
    const int scol  = quad * 8;
    const long aoff0 = (long)(m0 + srow0) * D_MODEL + scol;
    const long aoff1 = aoff0 + (long)64 * D_MODEL;
    const long boff0 = (long)(n0 + srow0) * D_MODEL + scol;
    const long boff1 = boff0 + (long)64 * D_MODEL;
    const int dst = wave * 512 + lane * 8;

    f32x4 acc[4][4];
    #pragma unroll
    for (int i = 0; i < 4; i++)
        #pragma unroll
        for (int j = 0; j < 4; j++)
            acc[i][j] = (f32x4){0.f, 0.f, 0.f, 0.f};

    GL16(A + aoff0, &As[0][dst]);
    GL16(A + aoff1, &As[0][dst + 2048]);
    GL16(W + boff0, &Bs[0][dst]);
    GL16(W + boff1, &Bs[0][dst + 2048]);

    for (int it = 0; it < KITER; it++) {
        const int cur = it & 1;
        __syncthreads();
        if (it + 1 < KITER) {
            const int k0 = (it + 1) * BK;
            const int nxt = cur ^ 1;
            GL16(A + aoff0 + k0, &As[nxt][dst]);
            GL16(A + aoff1 + k0, &As[nxt][dst + 2048]);
            GL16(W + boff0 + k0, &Bs[nxt][dst]);
            GL16(W + boff1 + k0, &Bs[nxt][dst + 2048]);
        }
        s16x8 af[4], bf[4];
        #pragma unroll
        for (int i = 0; i < 4; i++)
            af[i] = *reinterpret_cast<const s16x8*>(&As[cur][(wr * 4 + i) * 512 + lane * 8]);
        #pragma unroll
        for (int j = 0; j < 4; j++)
            bf[j] = *reinterpret_cast<const s16x8*>(&Bs[cur][(wc * 4 + j) * 512 + lane * 8]);
        #pragma unroll
        for (int i = 0; i < 4; i++)
            #pragma unroll
            for (int j = 0; j < 4; j++)
                acc[i][j] = __builtin_amdgcn_mfma_f32_16x16x32_bf16(af[i], bf[j], acc[i][j], 0, 0, 0);
    }

    #pragma unroll
    for (int i = 0; i < 4; i++)
        #pragma unroll
        for (int j = 0; j < 4; j++)
            #pragma unroll
            for (int r = 0; r < 4; r++) {
                const int gm = m0 + wr * 64 + i * 16 + quad * 4 + r;
                const int gn = n0 + wc * 64 + j * 16 + rlo;
                outF[(long)gm * D_MODEL + gn] =
                    acc[i][j][r] + bias[gn] + resid[(long)gm * D_MODEL + gn];
            }
}

// ---------------- flash attention: 128q block, 4 waves x 32q, P-streaming -------
#define PSTR 72

__global__ __launch_bounds__(256, 3)
void flash_attn_mfma(const u16* __restrict__ Qg, const u16* __restrict__ Kg,
                     const u16* __restrict__ VtG, u16* __restrict__ C)
{
    __shared__ __align__(16) u16 smem[20992];
    u16* KsB   = &smem[4608];     // 2 x 4096
    u16* VtBuf = &smem[12800];    // 2 x 4096

    const int t    = threadIdx.x;
    const int lane = t & 63;
    const int wave = t >> 6;
    const int quad = lane >> 4;
    const int rlo  = lane & 15;
    const int qt = blockIdx.x, h = blockIdx.y, b = blockIdx.z;
    const long colbase = (long)h * DK;
    const long rowb    = (long)b * SEQ;
    const long qrow0   = rowb + (long)qt * 128;
    const u16* kg    = Kg + rowb * D_MODEL + colbase;
    const u16* vbase = VtG + (long)(b * 16 + h) * 64 * 2048;
    u16* myPs = &smem[wave * 1152];   // 16 rows x PSTR, wave-private

    const long koff = (long)(wave * 16 + rlo) * D_MODEL + quad * 8;
    const long voff = (long)(wave * 16 + rlo) * 2048 + quad * 8;
    const int  dkv  = wave * 512 + lane * 8;

    // ---- K/V tile 0 DMA ----
    GL16(kg + koff,         &KsB[dkv]);
    GL16(kg + koff + 32,    &KsB[dkv + 2048]);
    GL16(vbase + voff,      &VtBuf[dkv]);
    GL16(vbase + voff + 32, &VtBuf[dkv + 2048]);

    // ---- Q frags direct from global (Q pre-scaled by C2 in projection) ----
    s16x8 bfq[2][2];
    #pragma unroll
    for (int mi = 0; mi < 2; mi++)
        #pragma unroll
        for (int ks = 0; ks < 2; ks++)
            bfq[mi][ks] = *reinterpret_cast<const s16x8*>(
                Qg + (qrow0 + wave * 32 + mi * 16 + rlo) * D_MODEL +
                colbase + ks * 32 + quad * 8);

    s16x8 ones;
    #pragma unroll
    for (int e = 0; e < 8; e++) ones[e] = (short)0x3F80;

    float m2[2] = {-INFINITY, -INFINITY};
    f32x4 o[2][4], o5[2];
    #pragma unroll
    for (int mi = 0; mi < 2; mi++) {
        o5[mi] = (f32x4){0.f, 0.f, 0.f, 0.f};
        #pragma unroll
        for (int db = 0; db < 4; db++)
            o[mi][db] = (f32x4){0.f, 0.f, 0.f, 0.f};
    }

    for (int kt = 0; kt < SEQ / 64; kt++) {
        const int cur = kt & 1;
        __syncthreads();   // drains DMA into buf cur
        if (kt + 1 < SEQ / 64) {
            const long kv0 = (long)(kt + 1) * 64;
            const int nb = cur ^ 1;
            GL16(kg + kv0 * D_MODEL + koff,      &KsB[nb * 4096 + dkv]);
            GL16(kg + kv0 * D_MODEL + koff + 32, &KsB[nb * 4096 + dkv + 2048]);
            GL16(vbase + kv0 + voff,             &VtBuf[nb * 4096 + dkv]);
            GL16(vbase + kv0 + voff + 32,        &VtBuf[nb * 4096 + dkv + 2048]);
        }
        const u16* Ks  = &KsB[cur * 4096];
        const u16* Vts = &VtBuf[cur * 4096];

        // ---- K and V frags (lane-linear, conflict-free b128) ----
        s16x8 afk[2][4], bfv[4][2];
        #pragma unroll
        for (int ks = 0; ks < 2; ks++)
            #pragma unroll
            for (int kb = 0; kb < 4; kb++)
                afk[ks][kb] = *reinterpret_cast<const s16x8*>(
                    &Ks[ks * 2048 + kb * 512 + lane * 8]);
        #pragma unroll
        for (int db = 0; db < 4; db++)
            #pragma unroll
            for (int ks = 0; ks < 2; ks++)
                bfv[db][ks] = *reinterpret_cast<const s16x8*>(
                    &Vts[ks * 2048 + db * 512 + lane * 8]);

        // ---- per-mi: S^T -> softmax -> P stream -> PV ----
        #pragma unroll
        for (int mi = 0; mi < 2; mi++) {
            f32x4 sc[4];
            #pragma unroll
            for (int kb = 0; kb < 4; kb++) sc[kb] = (f32x4){0.f, 0.f, 0.f, 0.f};
            #pragma unroll
            for (int ks = 0; ks < 2; ks++)
                #pragma unroll
                for (int kb = 0; kb < 4; kb++)
                    sc[kb] = __builtin_amdgcn_mfma_f32_16x16x32_bf16(
                        afk[ks][kb], bfq[mi][ks], sc[kb], 0, 0, 0);

            float rmax = sc[0][0];
            #pragma unroll
            for (int kb = 0; kb < 4; kb++)
                #pragma unroll
                for (int r = 0; r < 4; r++)
                    rmax = fmaxf(rmax, sc[kb][r]);
            rmax = fmaxf(rmax, __shfl_xor(rmax, 16));
            rmax = fmaxf(rmax, __shfl_xor(rmax, 32));
            const float mnew = fmaxf(m2[mi], rmax);
            const float alpha = EXP2(m2[mi] - mnew);
            m2[mi] = mnew;
            #pragma unroll
            for (int kb = 0; kb < 4; kb++) {
                float p0 = EXP2(sc[kb][0] - mnew);
                float p1 = EXP2(sc[kb][1] - mnew);
                float p2 = EXP2(sc[kb][2] - mnew);
                float p3 = EXP2(sc[kb][3] - mnew);
                uint2 wv2;
                wv2.x = pack2_trunc(p0, p1);
                wv2.y = pack2_trunc(p2, p3);
                *reinterpret_cast<uint2*>(&myPs[rlo * PSTR + kb * 16 + quad * 4]) = wv2;
            }

            // read A-frags of P (in-wave ds ordering; no barrier)
            s16x8 afp[2];
            #pragma unroll
            for (int ks = 0; ks < 2; ks++)
                afp[ks] = *reinterpret_cast<const s16x8*>(
                    &myPs[rlo * PSTR + ks * 32 + quad * 8]);

            // rescale O/l by alpha (broadcast from lane with rlo = q)
            #pragma unroll
            for (int r = 0; r < 4; r++) {
                const float ar = __shfl(alpha, (lane & 48) | (quad * 4 + r));
                #pragma unroll
                for (int db = 0; db < 4; db++)
                    o[mi][db][r] *= ar;
                o5[mi][r] *= ar;
            }

            // PV + ones column
            #pragma unroll
            for (int ks = 0; ks < 2; ks++) {
                #pragma unroll
                for (int db = 0; db < 4; db++)
                    o[mi][db] = __builtin_amdgcn_mfma_f32_16x16x32_bf16(
                        afp[ks], bfv[db][ks], o[mi][db], 0, 0, 0);
                o5[mi] = __builtin_amdgcn_mfma_f32_16x16x32_bf16(
                    afp[ks], ones, o5[mi], 0, 0, 0);
            }
        }
    }

    // ---- epilogue: O / l (l column-replicated -> no shuffles) ----
    #pragma unroll
    for (int mi = 0; mi < 2; mi++)
        #pragma unroll
        for (int r = 0; r < 4; r++) {
            const float inv = 1.f / o5[mi][r];
            const long grow = qrow0 + wave * 32 + mi * 16 + quad * 4 + r;
            #pragma unroll
            for (int db = 0; db < 4; db++)
                C[grow * D_MODEL + colbase + db * 16 + rlo] = f2b(o[mi][db][r] * inv);
        }
}

// ---------------- row LayerNorm in-place ----------------------------------------
__global__ __launch_bounds__(256)
void ln_inplace(float* __restrict__ Y, const float* __restrict__ gamma,
                const float* __restrict__ beta)
{
    const int row = blockIdx.x, t = threadIdx.x;
    float4 v = reinterpret_cast<float4*>(Y + (long)row * D_MODEL)[t];
    float s  = v.x + v.y + v.z + v.w;
    float ss = v.x * v.x + v.y * v.y + v.z * v.z + v.w * v.w;
    #pragma unroll
    for (int off = 32; off > 0; off >>= 1) {
        s  += __shfl_down(s, off, 64);
        ss += __shfl_down(ss, off, 64);
    }
    __shared__ float rs[4], rss[4];
    const int lane = t & 63, w = t >> 6;
    if (lane == 0) { rs[w] = s; rss[w] = ss; }
    __syncthreads();
    const float tot  = rs[0] + rs[1] + rs[2] + rs[3];
    const float tot2 = rss[0] + rss[1] + rss[2] + rss[3];
    const float mu   = tot * (1.f / D_MODEL);
    const float var  = tot2 * (1.f / D_MODEL) - mu * mu;
    const float rstd = rsqrtf(var + 1e-5f);
    const float4 g  = reinterpret_cast<const float4*>(gamma)[t];
    const float4 bb = reinterpret_cast<const float4*>(beta)[t];
    v.x = (v.x - mu) * rstd * g.x + bb.x;
    v.y = (v.y - mu) * rstd * g.y + bb.y;
    v.z = (v.z - mu) * rstd * g.z + bb.z;
    v.w = (v.w - mu) * rstd * g.w + bb.w;
    reinterpret_cast<float4*>(Y + (long)row * D_MODEL)[t] = v;
}

extern "C" void kernel_launch(void* const* d_in, const int* in_sizes, int n_in,
                              void* d_out, int out_size, void* d_ws, size_t ws_size,
                              hipStream_t stream)
{
    const float* x     = (const float*)d_in[0];
    const float* Wq    = (const float*)d_in[1];
    const float* bq    = (const float*)d_in[2];
    const float* Wk    = (const float*)d_in[3];
    const float* bk    = (const float*)d_in[4];
    const float* Wv    = (const float*)d_in[5];
    const float* bv    = (const float*)d_in[6];
    const float* Wo    = (const float*)d_in[7];
    const float* bo    = (const float*)d_in[8];
    const float* gamma = (const float*)d_in[9];
    const float* beta  = (const float*)d_in[10];
    float* out = (float*)d_out;

    u16* ws  = (u16*)d_ws;
    u16* xb  = ws;
    u16* Wqb = xb  + (size_t)MROWS * D_MODEL;
    u16* Wkb = Wqb + (size_t)D_MODEL * D_MODEL;
    u16* Wvb = Wkb + (size_t)D_MODEL * D_MODEL;
    u16* Wob = Wvb + (size_t)D_MODEL * D_MODEL;
    u16* Qb  = Wob + (size_t)D_MODEL * D_MODEL;
    u16* Kb  = Qb  + (size_t)MROWS * D_MODEL;
    u16* VtB = Kb  + (size_t)MROWS * D_MODEL;    // V^T in [b][h][d][s] layout
    u16* Cb  = VtB + (size_t)MROWS * D_MODEL;

    cvt_all<<<12288, 256, 0, stream>>>(x, Wq, Wk, Wv, Wo, xb, Wqb, Wkb, Wvb, Wob);

    gemm_qkv<<<dim3(24, 32), 512, 0, stream>>>(xb, Wqb, Wkb, Wvb, bq, bk, bv,
                                               Qb, Kb, VtB);

    flash_attn_mfma<<<dim3(SEQ / 128, NHEADS, BATCH), 256, 0, stream>>>(Qb, Kb, VtB, Cb);

    gemm_o<<<dim3(8, 64), 256, 0, stream>>>(Cb, Wob, bo, x, out);

    ln_inplace<<<MROWS, 256, 0, stream>>>(out, gamma, beta);
}